// Round 1
// baseline (1886.918 us; speedup 1.0000x reference)
//
#include <hip/hip_runtime.h>
#include <hip/hip_bf16.h>
#include <hip/hip_fp16.h>

typedef unsigned short u16;
typedef unsigned int u32;
typedef short s16x8 __attribute__((ext_vector_type(8)));
typedef float f32x4 __attribute__((ext_vector_type(4)));

#define FE_LD 2944
#define EDGE_LD 2816

static __device__ __forceinline__ __half2 u_as_h2(u32 u){ return __builtin_bit_cast(__half2, u); }

// ---------------------------------------------------------------------------
// Generic bf16 MFMA GEMM: C[M=4096][N] = A[M][K] * B^T[N][K] (+bias), K%64==0.
// 128x128 tile, 4 waves (2x2), 4x4 frags of 16x16x32. XOR-swizzled LDS.
// ---------------------------------------------------------------------------
__global__ __launch_bounds__(256) void gemm_kernel(
    const u16* __restrict__ A, int lda,
    const u16* __restrict__ B, int ldb,
    int K, int N,
    float* __restrict__ outF, __hip_bfloat16* __restrict__ outB, int ldc,
    const float* __restrict__ bias)
{
  __shared__ __align__(16) u16 As[128*64];
  __shared__ __align__(16) u16 Bs[128*64];
  const int tid = threadIdx.x;
  const int w = tid >> 6, lane = tid & 63;
  const int wm = w >> 1, wn = w & 1;
  const long bm = (long)blockIdx.x * 128;
  const long bn = (long)blockIdx.y * 128;
  f32x4 acc[4][4] = {};

  for (int k0 = 0; k0 < K; k0 += 64) {
    #pragma unroll
    for (int rr = 0; rr < 4; rr++) {
      int idx = rr * 256 + tid;
      int row = idx >> 3;
      int g   = idx & 7;                       // 16B group within row
      int dst = row * 64 + ((g ^ (row & 7)) << 3);   // swizzled element offset
      *(uint4*)&As[dst] = *(const uint4*)(A + (bm + row) * (long)lda + k0 + g * 8);
      *(uint4*)&Bs[dst] = *(const uint4*)(B + (bn + row) * (long)ldb + k0 + g * 8);
    }
    __syncthreads();
    #pragma unroll
    for (int kk = 0; kk < 2; kk++) {
      s16x8 af[4], bfr[4];
      #pragma unroll
      for (int i = 0; i < 4; i++) {
        int ra = wm * 64 + i * 16 + (lane & 15);
        int rb = wn * 64 + i * 16 + (lane & 15);
        int gg = kk * 4 + (lane >> 4);
        af[i]  = *(const s16x8*)&As[ra * 64 + ((gg ^ (ra & 7)) << 3)];
        bfr[i] = *(const s16x8*)&Bs[rb * 64 + ((gg ^ (rb & 7)) << 3)];
      }
      #pragma unroll
      for (int i = 0; i < 4; i++)
        #pragma unroll
        for (int j = 0; j < 4; j++)
          acc[i][j] = __builtin_amdgcn_mfma_f32_16x16x32_bf16(af[i], bfr[j], acc[i][j], 0, 0, 0);
    }
    __syncthreads();
  }

  #pragma unroll
  for (int i = 0; i < 4; i++)
    #pragma unroll
    for (int j = 0; j < 4; j++)
      #pragma unroll
      for (int v = 0; v < 4; v++) {
        long rr = bm + wm * 64 + i * 16 + (lane >> 4) * 4 + v;
        int  cc = (int)bn + wn * 64 + j * 16 + (lane & 15);
        if (cc < N) {
          float val = acc[i][j][v] + (bias ? bias[cc] : 0.f);
          if (outF) outF[rr * (long)ldc + cc] = val;
          else      outB[rr * (long)ldc + cc] = __float2bfloat16(val);
        }
      }
}

// ---------------------------------------------------------------------------
// Tiled transpose + cast fp32 -> bf16, with zero padding and optional row
// remap (for dec: k<split -> split_off+k else k-split).
// dst[n][k] = src[srck][n]
// ---------------------------------------------------------------------------
__global__ void transpose_cast(const float* __restrict__ src, __hip_bfloat16* __restrict__ dst,
                               int srcK, int srcN, int dstR, int dstC, int split, int split_off)
{
  __shared__ float tile[32][33];
  const int kt = blockIdx.x * 32, nt = blockIdx.y * 32;
  const int tx = threadIdx.x & 31, ty = threadIdx.x >> 5;
  for (int i = ty; i < 32; i += 8) {
    int k = kt + i;
    int srck = (k < split) ? (split_off + k) : (k - split);
    int n = nt + tx;
    tile[i][tx] = (srck < srcK && n < srcN) ? src[(size_t)srck * srcN + n] : 0.f;
  }
  __syncthreads();
  for (int i = ty; i < 32; i += 8) {
    int n = nt + i, k = kt + tx;
    if (n < dstR && k < dstC)
      dst[(size_t)n * dstC + k] = __float2bfloat16(tile[tx][i]);
  }
}

// ---------------------------------------------------------------------------
// Pack whh fp32 [2][256][1024] -> f16 pairs:
//   wreg [2][1024][96]  : k 0..191   (column-major per gate column)
//   wtail[2][32][1024]  : k 192..255
// ---------------------------------------------------------------------------
__global__ void pack_whh(const float* __restrict__ whh, u32* __restrict__ wreg, u32* __restrict__ wtail)
{
  const int d = blockIdx.y;
  const int j = blockIdx.x * 256 + threadIdx.x;
  const float* s = whh + (size_t)d * 256 * 1024;
  for (int kk = 0; kk < 96; kk++) {
    __half2 h = __floats2half2_rn(s[(2 * kk) * 1024 + j], s[(2 * kk + 1) * 1024 + j]);
    wreg[((size_t)(d * 1024 + j)) * 96 + kk] = __builtin_bit_cast(u32, h);
  }
  for (int kk = 0; kk < 32; kk++) {
    __half2 h = __floats2half2_rn(s[(192 + 2 * kk) * 1024 + j], s[(193 + 2 * kk) * 1024 + j]);
    wtail[(size_t)(d * 32 + kk) * 1024 + j] = __builtin_bit_cast(u32, h);
  }
}

// ---------------------------------------------------------------------------
// prep: softmax(151), probs->bf16 (padded 192), conf=max(probs[1:]),
// pos = relu(BN(center_size(boxes)) @ pos_w + pos_b), fmaps -> FE bf16.
// FE layout: [enc 0..512 | fmaps 512..2560 | embed 2560..2760 | pos 2760..2888 | pad]
// ---------------------------------------------------------------------------
__global__ void prep_kernel(
    const float* __restrict__ logits, const float* __restrict__ fmaps,
    const float* __restrict__ boxes,
    const float* __restrict__ bn_g, const float* __restrict__ bn_b,
    const float* __restrict__ bn_m, const float* __restrict__ bn_v,
    const float* __restrict__ pos_w, const float* __restrict__ pos_b,
    __hip_bfloat16* __restrict__ FE, __hip_bfloat16* __restrict__ probsb,
    float* __restrict__ conf)
{
  __shared__ float red[256];
  const int row = blockIdx.x, t = threadIdx.x;
  float v = (t < 151) ? logits[(size_t)row * 151 + t] : -3.0e38f;
  red[t] = v; __syncthreads();
  for (int s = 128; s > 0; s >>= 1) { if (t < s) red[t] = fmaxf(red[t], red[t + s]); __syncthreads(); }
  float mx = red[0]; __syncthreads();
  float p = (t < 151) ? expf(v - mx) : 0.f;
  red[t] = p; __syncthreads();
  for (int s = 128; s > 0; s >>= 1) { if (t < s) red[t] += red[t + s]; __syncthreads(); }
  float sum = red[0]; __syncthreads();
  p = p / sum;
  if (t < 192) probsb[(size_t)row * 192 + t] = __float2bfloat16((t < 151) ? p : 0.f);
  red[t] = (t >= 1 && t < 151) ? p : 0.f; __syncthreads();
  for (int s = 128; s > 0; s >>= 1) { if (t < s) red[t] = fmaxf(red[t], red[t + s]); __syncthreads(); }
  if (t == 0) conf[row] = red[0];

  if (t < 128) {
    float x1 = boxes[row * 4 + 0], y1 = boxes[row * 4 + 1];
    float x2 = boxes[row * 4 + 2], y2 = boxes[row * 4 + 3];
    float cs[4] = { (x1 + x2) * 0.5f, (y1 + y2) * 0.5f, x2 - x1, y2 - y1 };
    float a = pos_b[t];
    #pragma unroll
    for (int j = 0; j < 4; j++) {
      float cn = (cs[j] - bn_m[j]) * rsqrtf(bn_v[j] + 1e-5f) * bn_g[j] + bn_b[j];
      a += cn * pos_w[j * 128 + t];
    }
    FE[(size_t)row * FE_LD + 2760 + t] = __float2bfloat16(fmaxf(a, 0.f));
  }
  for (int c0 = t; c0 < 2048; c0 += 256)
    FE[(size_t)row * FE_LD + 512 + c0] = __float2bfloat16(fmaps[(size_t)row * 2048 + c0]);
}

// ---------------------------------------------------------------------------
// Per-image bitonic sort of conf desc (tie: index asc) -> perm (global rows).
// ---------------------------------------------------------------------------
__global__ void sort_kernel(const float* __restrict__ conf, int* __restrict__ perm)
{
  __shared__ float key[128];
  __shared__ int   idx[128];
  const int b = blockIdx.x, t = threadIdx.x;
  key[t] = conf[b * 128 + t]; idx[t] = t;
  __syncthreads();
  for (int k = 2; k <= 128; k <<= 1)
    for (int j = k >> 1; j > 0; j >>= 1) {
      int ixj = t ^ j;
      if (ixj > t) {
        bool up = (t & k) == 0;
        float ka = key[t], kb = key[ixj];
        int ia = idx[t], ib = idx[ixj];
        bool before = (ka > kb) || (ka == kb && ia < ib); // desc, stable
        if (before != up) { key[t] = kb; key[ixj] = ka; idx[t] = ib; idx[ixj] = ia; }
      }
      __syncthreads();
    }
  perm[b * 128 + t] = b * 128 + idx[t];
}

// ---------------------------------------------------------------------------
// LSTM scan. 64 blocks = (img 32) x (dir 2), 1024 threads (16 waves).
// Thread j owns gate column j. whh column: 192 k in regs (f16x2), 64 k in LDS.
// ---------------------------------------------------------------------------
__global__ __launch_bounds__(1024) void rec_kernel(
    const float* __restrict__ P,          // [4096][2048] pre-activations (+bias)
    const int* __restrict__ perm,         // [4096] global rows
    const u32* __restrict__ wreg,         // [2][1024][96]
    const u32* __restrict__ wtail,        // [2][32][1024]
    int gatherPerm, int outPerm,
    __hip_bfloat16* __restrict__ out_bf, int out_ld,
    float* __restrict__ out_f32, int f32_ld, int f32_off)
{
  __shared__ __align__(16) u32 wt[32][1024];
  __shared__ float g_lds[1024];
  __shared__ __align__(16) __half h_lds[256];
  const int tid = threadIdx.x;
  const int img = blockIdx.x & 31, dir = blockIdx.x >> 5;

  u32 wv[96];
  {
    const u32* wp = wreg + ((size_t)(dir * 1024 + tid)) * 96;
    #pragma unroll
    for (int i = 0; i < 96; i++) wv[i] = wp[i];
  }
  {
    const u32* tp = wtail + (size_t)dir * 32768;
    for (int i = tid; i < 32768; i += 1024) ((u32*)wt)[i] = tp[i];
  }
  if (tid < 256) h_lds[tid] = __float2half(0.f);
  float c = 0.f;
  __syncthreads();

  for (int t = 0; t < 128; t++) {
    const int st = dir ? (127 - t) : t;
    const int srow = img * 128 + st;
    const int prow = gatherPerm ? perm[srow] : srow;
    float g = P[(size_t)prow * 2048 + dir * 1024 + tid];

    __half2 a0 = __float2half2_rn(0.f), a1 = __float2half2_rn(0.f);
    const uint4* h4 = (const uint4*)h_lds;
    #pragma unroll
    for (int q = 0; q < 24; q++) {
      uint4 hv = h4[q];
      a0 = __hfma2(u_as_h2(hv.x), u_as_h2(wv[4 * q + 0]), a0);
      a1 = __hfma2(u_as_h2(hv.y), u_as_h2(wv[4 * q + 1]), a1);
      a0 = __hfma2(u_as_h2(hv.z), u_as_h2(wv[4 * q + 2]), a0);
      a1 = __hfma2(u_as_h2(hv.w), u_as_h2(wv[4 * q + 3]), a1);
    }
    #pragma unroll
    for (int q = 24; q < 32; q++) {
      uint4 hv = h4[q];
      int kk = 4 * (q - 24);
      a0 = __hfma2(u_as_h2(hv.x), u_as_h2(wt[kk + 0][tid]), a0);
      a1 = __hfma2(u_as_h2(hv.y), u_as_h2(wt[kk + 1][tid]), a1);
      a0 = __hfma2(u_as_h2(hv.z), u_as_h2(wt[kk + 2][tid]), a0);
      a1 = __hfma2(u_as_h2(hv.w), u_as_h2(wt[kk + 3][tid]), a1);
    }
    g += __low2float(a0) + __high2float(a0) + __low2float(a1) + __high2float(a1);
    g_lds[tid] = g;
    __syncthreads();

    if (tid < 256) {
      float gi = g_lds[tid], gf = g_lds[256 + tid], gg = g_lds[512 + tid], go = g_lds[768 + tid];
      float si = 1.f / (1.f + expf(-gi));
      float sf = 1.f / (1.f + expf(-gf));
      float so = 1.f / (1.f + expf(-go));
      c = sf * c + si * tanhf(gg);
      float h = so * tanhf(c);
      h_lds[tid] = __float2half(h);
      const int orow = outPerm ? perm[srow] : srow;
      if (out_bf)  out_bf[(size_t)orow * out_ld + dir * 256 + tid] = __float2bfloat16(h);
      if (out_f32) out_f32[(size_t)orow * f32_ld + f32_off + dir * 256 + tid] = h;
    }
    __syncthreads();
  }
}

// ---------------------------------------------------------------------------
// argmax over obj_dists[:,1:151) -> preds (first max wins, like jnp.argmax)
// ---------------------------------------------------------------------------
__global__ void argmax_kernel(const float* __restrict__ dists, int* __restrict__ preds)
{
  const int row = blockIdx.x * 4 + (threadIdx.x >> 6);
  const int lane = threadIdx.x & 63;
  float best = -3.4e38f; int bi = 1000;
  for (int cc = 1 + lane; cc < 151; cc += 64) {
    float v = dists[(size_t)row * 663 + cc];
    if (v > best) { best = v; bi = cc; }
  }
  for (int off = 32; off > 0; off >>= 1) {
    float ov = __shfl_down(best, off);
    int   oi = __shfl_down(bi, off);
    if (ov > best || (ov == best && oi < bi)) { best = ov; bi = oi; }
  }
  if (lane == 0) preds[row] = bi;
}

// ---------------------------------------------------------------------------
// edge_in = [embed2[pred] (200) | enc (512, from FE) | fmaps (2048)] bf16
// ---------------------------------------------------------------------------
__global__ void edge_build(const int* __restrict__ preds,
                           const float* __restrict__ embed2,
                           const float* __restrict__ fmaps,
                           const __hip_bfloat16* __restrict__ FE,
                           __hip_bfloat16* __restrict__ EDGE)
{
  const int row = blockIdx.x, t = threadIdx.x;
  const int pr = preds[row];
  for (int c0 = t; c0 < 200; c0 += 256)
    EDGE[(size_t)row * EDGE_LD + c0] = __float2bfloat16(embed2[(size_t)pr * 200 + c0]);
  for (int c0 = t; c0 < 512; c0 += 256)
    EDGE[(size_t)row * EDGE_LD + 200 + c0] = FE[(size_t)row * FE_LD + c0];
  for (int c0 = t; c0 < 2048; c0 += 256)
    EDGE[(size_t)row * EDGE_LD + 712 + c0] = __float2bfloat16(fmaps[(size_t)row * 2048 + c0]);
}

// ---------------------------------------------------------------------------
extern "C" void kernel_launch(void* const* d_in, const int* in_sizes, int n_in,
                              void* d_out, int out_size, void* d_ws, size_t ws_size,
                              hipStream_t stream)
{
  const float* obj_fmaps    = (const float*)d_in[0];
  const float* obj_logits   = (const float*)d_in[1];
  const float* boxes        = (const float*)d_in[2];
  const float* obj_embed_w  = (const float*)d_in[4];
  const float* obj_embed2_w = (const float*)d_in[5];
  const float* bn_g = (const float*)d_in[6];
  const float* bn_b = (const float*)d_in[7];
  const float* bn_m = (const float*)d_in[8];
  const float* bn_v = (const float*)d_in[9];
  const float* pos_w = (const float*)d_in[10];
  const float* pos_b = (const float*)d_in[11];
  const float* obj_wih0 = (const float*)d_in[12];
  const float* obj_whh0 = (const float*)d_in[13];
  const float* obj_b0   = (const float*)d_in[14];
  const float* obj_wih1 = (const float*)d_in[15];
  const float* obj_whh1 = (const float*)d_in[16];
  const float* obj_b1   = (const float*)d_in[17];
  const float* edge_wih0 = (const float*)d_in[18];
  const float* edge_whh0 = (const float*)d_in[19];
  const float* edge_b0   = (const float*)d_in[20];
  const float* edge_wih1 = (const float*)d_in[21];
  const float* edge_whh1 = (const float*)d_in[22];
  const float* edge_b1   = (const float*)d_in[23];
  const float* dec_w = (const float*)d_in[24];
  const float* dec_b = (const float*)d_in[25];
  float* out = (float*)d_out;

  char* ws = (char*)d_ws;
  auto alloc = [&](size_t bytes) -> char* {
    char* p = ws; ws += (bytes + 255) & ~(size_t)255; return p;
  };
  __hip_bfloat16* FE     = (__hip_bfloat16*)alloc(4096ull * FE_LD * 2);
  __hip_bfloat16* EDGE   = (__hip_bfloat16*)alloc(4096ull * EDGE_LD * 2);
  float*          Pbuf   = (float*)alloc(4096ull * 2048 * 4);
  __hip_bfloat16* hseq   = (__hip_bfloat16*)alloc(4096ull * 512 * 2);
  __hip_bfloat16* probsb = (__hip_bfloat16*)alloc(4096ull * 192 * 2);
  __hip_bfloat16* wih0T  = (__hip_bfloat16*)alloc(2048ull * 2432 * 2);
  __hip_bfloat16* wih1T  = (__hip_bfloat16*)alloc(2048ull * 512 * 2);
  __hip_bfloat16* ewih0T = (__hip_bfloat16*)alloc(2048ull * 2816 * 2);
  __hip_bfloat16* ewih1T = (__hip_bfloat16*)alloc(2048ull * 512 * 2);
  __hip_bfloat16* embedT = (__hip_bfloat16*)alloc(256ull * 192 * 2);
  __hip_bfloat16* decT   = (__hip_bfloat16*)alloc(256ull * 2944 * 2);
  u32* whh0pk  = (u32*)alloc(2ull * (1024 * 96 + 32 * 1024) * 4);
  u32* whh1pk  = (u32*)alloc(2ull * (1024 * 96 + 32 * 1024) * 4);
  u32* ewhh0pk = (u32*)alloc(2ull * (1024 * 96 + 32 * 1024) * 4);
  u32* ewhh1pk = (u32*)alloc(2ull * (1024 * 96 + 32 * 1024) * 4);
  int*   perm  = (int*)alloc(4096 * 4);
  float* conf  = (float*)alloc(4096 * 4);
  int*   preds = (int*)alloc(4096 * 4);
  (void)in_sizes; (void)n_in; (void)out_size; (void)ws_size;

  auto tr = [&](const float* src, __hip_bfloat16* dst, int srcK, int srcN,
                int dstR, int dstC, int split, int soff) {
    dim3 g((dstC + 31) / 32, (dstR + 31) / 32);
    transpose_cast<<<g, dim3(256), 0, stream>>>(src, dst, srcK, srcN, dstR, dstC, split, soff);
  };
  for (int d = 0; d < 2; d++) {
    tr(obj_wih0 + (size_t)d * 2376 * 1024, wih0T + (size_t)d * 1024 * 2432, 2376, 1024, 1024, 2432, 0, 0);
    tr(obj_wih1 + (size_t)d * 512 * 1024,  wih1T + (size_t)d * 1024 * 512,  512, 1024, 1024, 512, 0, 0);
    tr(edge_wih0 + (size_t)d * 2760 * 1024, ewih0T + (size_t)d * 1024 * 2816, 2760, 1024, 1024, 2816, 0, 0);
    tr(edge_wih1 + (size_t)d * 512 * 1024,  ewih1T + (size_t)d * 1024 * 512,  512, 1024, 1024, 512, 0, 0);
  }
  tr(obj_embed_w, embedT, 151, 200, 256, 192, 0, 0);
  tr(dec_w, decT, 2888, 151, 256, 2944, 512, 2376);  // [enc|feats] ordering remap

  auto pk = [&](const float* whh, u32* dst) {
    pack_whh<<<dim3(4, 2), dim3(256), 0, stream>>>(whh, dst, dst + 2 * 1024 * 96);
  };
  pk(obj_whh0, whh0pk); pk(obj_whh1, whh1pk); pk(edge_whh0, ewhh0pk); pk(edge_whh1, ewhh1pk);

  prep_kernel<<<dim3(4096), dim3(256), 0, stream>>>(
      obj_logits, obj_fmaps, boxes, bn_g, bn_b, bn_m, bn_v, pos_w, pos_b, FE, probsb, conf);
  sort_kernel<<<dim3(32), dim3(128), 0, stream>>>(conf, perm);

  auto gemm = [&](const void* A, int lda, const void* B, int ldb, int K, int N,
                  float* oF, __hip_bfloat16* oB, int ldc, const float* bias) {
    dim3 g(32, (N + 127) / 128);
    gemm_kernel<<<g, dim3(256), 0, stream>>>(
        (const u16*)A, lda, (const u16*)B, ldb, K, N, oF, oB, ldc, bias);
  };
  auto rec = [&](const float* P, const u32* wpk, int gat, int op,
                 __hip_bfloat16* ob, int old_, float* of, int fld, int foff) {
    rec_kernel<<<dim3(64), dim3(1024), 0, stream>>>(
        P, perm, wpk, wpk + 2 * 1024 * 96, gat, op, ob, old_, of, fld, foff);
  };

  // obj_embed -> FE cols [2560,2760)
  gemm(probsb, 192, embedT, 192, 192, 200, nullptr, FE + 2560, FE_LD, nullptr);
  // obj layer 0
  gemm((const u16*)FE + 512, FE_LD, wih0T, 2432, 2432, 2048, Pbuf, nullptr, 2048, obj_b0);
  rec(Pbuf, whh0pk, 1, 0, hseq, 512, nullptr, 0, 0);
  // obj layer 1 -> enc into FE cols [0,512)
  gemm(hseq, 512, wih1T, 512, 512, 2048, Pbuf, nullptr, 2048, obj_b1);
  rec(Pbuf, whh1pk, 0, 1, FE, FE_LD, nullptr, 0, 0);
  // decoder -> out cols [0,151)
  gemm(FE, FE_LD, decT, 2944, 2944, 151, out, nullptr, 663, dec_b);
  argmax_kernel<<<dim3(1024), dim3(256), 0, stream>>>(out, preds);
  edge_build<<<dim3(4096), dim3(256), 0, stream>>>(preds, obj_embed2_w, obj_fmaps, FE, EDGE);
  // edge layer 0
  gemm(EDGE, EDGE_LD, ewih0T, 2816, 2816, 2048, Pbuf, nullptr, 2048, edge_b0);
  rec(Pbuf, ewhh0pk, 1, 0, hseq, 512, nullptr, 0, 0);
  // edge layer 1 -> out cols [151,663)
  gemm(hseq, 512, ewih1T, 512, 512, 2048, Pbuf, nullptr, 2048, edge_b1);
  rec(Pbuf, ewhh1pk, 0, 1, nullptr, 0, out, 663, 151);
}

// Round 2
// 1882.389 us; speedup vs baseline: 1.0024x; 1.0024x over previous
//
#include <hip/hip_runtime.h>
#include <hip/hip_bf16.h>
#include <hip/hip_fp16.h>

typedef unsigned short u16;
typedef unsigned int u32;
typedef short s16x8 __attribute__((ext_vector_type(8)));
typedef float f32x4 __attribute__((ext_vector_type(4)));

#define FE_LD 2944
#define EDGE_LD 2816

static __device__ __forceinline__ __half2 u_as_h2(u32 u){ return __builtin_bit_cast(__half2, u); }

static __device__ __forceinline__ float fsig(float x) {
  return __builtin_amdgcn_rcpf(1.f + __expf(-x));
}
static __device__ __forceinline__ float ftanh(float x) {
  return 1.f - 2.f * __builtin_amdgcn_rcpf(1.f + __expf(2.f * x));
}

// ---------------------------------------------------------------------------
// Generic bf16 MFMA GEMM: C[M=4096][N] = A[M][K] * B^T[N][K] (+bias), K%64==0.
// 128x128 tile, 4 waves (2x2), 4x4 frags of 16x16x32. XOR-swizzled LDS.
// ---------------------------------------------------------------------------
__global__ __launch_bounds__(256) void gemm_kernel(
    const u16* __restrict__ A, int lda,
    const u16* __restrict__ B, int ldb,
    int K, int N,
    float* __restrict__ outF, __hip_bfloat16* __restrict__ outB, int ldc,
    const float* __restrict__ bias)
{
  __shared__ __align__(16) u16 As[128*64];
  __shared__ __align__(16) u16 Bs[128*64];
  const int tid = threadIdx.x;
  const int w = tid >> 6, lane = tid & 63;
  const int wm = w >> 1, wn = w & 1;
  const long bm = (long)blockIdx.x * 128;
  const long bn = (long)blockIdx.y * 128;
  f32x4 acc[4][4] = {};

  for (int k0 = 0; k0 < K; k0 += 64) {
    #pragma unroll
    for (int rr = 0; rr < 4; rr++) {
      int idx = rr * 256 + tid;
      int row = idx >> 3;
      int g   = idx & 7;                       // 16B group within row
      int dst = row * 64 + ((g ^ (row & 7)) << 3);   // swizzled element offset
      *(uint4*)&As[dst] = *(const uint4*)(A + (bm + row) * (long)lda + k0 + g * 8);
      *(uint4*)&Bs[dst] = *(const uint4*)(B + (bn + row) * (long)ldb + k0 + g * 8);
    }
    __syncthreads();
    #pragma unroll
    for (int kk = 0; kk < 2; kk++) {
      s16x8 af[4], bfr[4];
      #pragma unroll
      for (int i = 0; i < 4; i++) {
        int ra = wm * 64 + i * 16 + (lane & 15);
        int rb = wn * 64 + i * 16 + (lane & 15);
        int gg = kk * 4 + (lane >> 4);
        af[i]  = *(const s16x8*)&As[ra * 64 + ((gg ^ (ra & 7)) << 3)];
        bfr[i] = *(const s16x8*)&Bs[rb * 64 + ((gg ^ (rb & 7)) << 3)];
      }
      #pragma unroll
      for (int i = 0; i < 4; i++)
        #pragma unroll
        for (int j = 0; j < 4; j++)
          acc[i][j] = __builtin_amdgcn_mfma_f32_16x16x32_bf16(af[i], bfr[j], acc[i][j], 0, 0, 0);
    }
    __syncthreads();
  }

  #pragma unroll
  for (int i = 0; i < 4; i++)
    #pragma unroll
    for (int j = 0; j < 4; j++)
      #pragma unroll
      for (int v = 0; v < 4; v++) {
        long rr = bm + wm * 64 + i * 16 + (lane >> 4) * 4 + v;
        int  cc = (int)bn + wn * 64 + j * 16 + (lane & 15);
        if (cc < N) {
          float val = acc[i][j][v] + (bias ? bias[cc] : 0.f);
          if (outF) outF[rr * (long)ldc + cc] = val;
          else      outB[rr * (long)ldc + cc] = __float2bfloat16(val);
        }
      }
}

// ---------------------------------------------------------------------------
// Tiled transpose + cast fp32 -> bf16, with zero padding and optional row
// remap (for dec: k<split -> split_off+k else k-split).
// dst[n][k] = src[srck][n]
// ---------------------------------------------------------------------------
__global__ void transpose_cast(const float* __restrict__ src, __hip_bfloat16* __restrict__ dst,
                               int srcK, int srcN, int dstR, int dstC, int split, int split_off)
{
  __shared__ float tile[32][33];
  const int kt = blockIdx.x * 32, nt = blockIdx.y * 32;
  const int tx = threadIdx.x & 31, ty = threadIdx.x >> 5;
  for (int i = ty; i < 32; i += 8) {
    int k = kt + i;
    int srck = (k < split) ? (split_off + k) : (k - split);
    int n = nt + tx;
    tile[i][tx] = (srck < srcK && n < srcN) ? src[(size_t)srck * srcN + n] : 0.f;
  }
  __syncthreads();
  for (int i = ty; i < 32; i += 8) {
    int n = nt + i, k = kt + tx;
    if (n < dstR && k < dstC)
      dst[(size_t)n * dstC + k] = __float2bfloat16(tile[tx][i]);
  }
}

// ---------------------------------------------------------------------------
// Pack whh fp32 [2][256][1024] -> f16 pairs, layout [dir][kk=128][col=1024]:
//   wpk[(d*128+kk)*1024 + j] = (w[2kk][j], w[2kk+1][j])
// ---------------------------------------------------------------------------
__global__ void pack_whh(const float* __restrict__ whh, u32* __restrict__ wpk)
{
  const int d = blockIdx.y;
  const int j = blockIdx.x * 256 + threadIdx.x;
  const float* s = whh + (size_t)d * 256 * 1024;
  for (int kk = 0; kk < 128; kk++) {
    __half2 h = __floats2half2_rn(s[(2 * kk) * 1024 + j], s[(2 * kk + 1) * 1024 + j]);
    wpk[((size_t)d * 128 + kk) * 1024 + j] = __builtin_bit_cast(u32, h);
  }
}

// ---------------------------------------------------------------------------
// prep: softmax(151), probs->bf16 (padded 192), conf=max(probs[1:]),
// pos = relu(BN(center_size(boxes)) @ pos_w + pos_b), fmaps -> FE bf16.
// FE layout: [enc 0..512 | fmaps 512..2560 | embed 2560..2760 | pos 2760..2888 | pad]
// ---------------------------------------------------------------------------
__global__ void prep_kernel(
    const float* __restrict__ logits, const float* __restrict__ fmaps,
    const float* __restrict__ boxes,
    const float* __restrict__ bn_g, const float* __restrict__ bn_b,
    const float* __restrict__ bn_m, const float* __restrict__ bn_v,
    const float* __restrict__ pos_w, const float* __restrict__ pos_b,
    __hip_bfloat16* __restrict__ FE, __hip_bfloat16* __restrict__ probsb,
    float* __restrict__ conf)
{
  __shared__ float red[256];
  const int row = blockIdx.x, t = threadIdx.x;
  float v = (t < 151) ? logits[(size_t)row * 151 + t] : -3.0e38f;
  red[t] = v; __syncthreads();
  for (int s = 128; s > 0; s >>= 1) { if (t < s) red[t] = fmaxf(red[t], red[t + s]); __syncthreads(); }
  float mx = red[0]; __syncthreads();
  float p = (t < 151) ? expf(v - mx) : 0.f;
  red[t] = p; __syncthreads();
  for (int s = 128; s > 0; s >>= 1) { if (t < s) red[t] += red[t + s]; __syncthreads(); }
  float sum = red[0]; __syncthreads();
  p = p / sum;
  if (t < 192) probsb[(size_t)row * 192 + t] = __float2bfloat16((t < 151) ? p : 0.f);
  red[t] = (t >= 1 && t < 151) ? p : 0.f; __syncthreads();
  for (int s = 128; s > 0; s >>= 1) { if (t < s) red[t] = fmaxf(red[t], red[t + s]); __syncthreads(); }
  if (t == 0) conf[row] = red[0];

  if (t < 128) {
    float x1 = boxes[row * 4 + 0], y1 = boxes[row * 4 + 1];
    float x2 = boxes[row * 4 + 2], y2 = boxes[row * 4 + 3];
    float cs[4] = { (x1 + x2) * 0.5f, (y1 + y2) * 0.5f, x2 - x1, y2 - y1 };
    float a = pos_b[t];
    #pragma unroll
    for (int j = 0; j < 4; j++) {
      float cn = (cs[j] - bn_m[j]) * rsqrtf(bn_v[j] + 1e-5f) * bn_g[j] + bn_b[j];
      a += cn * pos_w[j * 128 + t];
    }
    FE[(size_t)row * FE_LD + 2760 + t] = __float2bfloat16(fmaxf(a, 0.f));
  }
  for (int c0 = t; c0 < 2048; c0 += 256)
    FE[(size_t)row * FE_LD + 512 + c0] = __float2bfloat16(fmaps[(size_t)row * 2048 + c0]);
}

// ---------------------------------------------------------------------------
// Per-image bitonic sort of conf desc (tie: index asc) -> perm (global rows).
// ---------------------------------------------------------------------------
__global__ void sort_kernel(const float* __restrict__ conf, int* __restrict__ perm)
{
  __shared__ float key[128];
  __shared__ int   idx[128];
  const int b = blockIdx.x, t = threadIdx.x;
  key[t] = conf[b * 128 + t]; idx[t] = t;
  __syncthreads();
  for (int k = 2; k <= 128; k <<= 1)
    for (int j = k >> 1; j > 0; j >>= 1) {
      int ixj = t ^ j;
      if (ixj > t) {
        bool up = (t & k) == 0;
        float ka = key[t], kb = key[ixj];
        int ia = idx[t], ib = idx[ixj];
        bool before = (ka > kb) || (ka == kb && ia < ib); // desc, stable
        if (before != up) { key[t] = kb; key[ixj] = ka; idx[t] = ib; idx[ixj] = ia; }
      }
      __syncthreads();
    }
  perm[b * 128 + t] = b * 128 + idx[t];
}

// ---------------------------------------------------------------------------
// LSTM scan. 64 blocks = (img 32) x (dir 2), 1024 threads (16 waves).
// Thread j owns gate column j. ALL 256 whh k-values in 128 f16x2 VGPRs.
// 2 barriers/step; P prefetched one step ahead; perm rows cached in LDS.
// ---------------------------------------------------------------------------
__global__ __launch_bounds__(1024, 4) void rec_kernel(
    const float* __restrict__ P,          // [4096][2048] pre-activations (+bias)
    const int* __restrict__ perm,         // [4096] global rows
    const u32* __restrict__ wpk,          // [2][128][1024]
    int gatherPerm, int outPerm,
    __hip_bfloat16* __restrict__ out_bf, int out_ld,
    float* __restrict__ out_f32, int f32_ld, int f32_off)
{
  __shared__ float g_lds[1024];
  __shared__ __align__(16) __half h_lds[256];
  __shared__ int prow_lds[128];
  const int tid = threadIdx.x;
  const int img = blockIdx.x & 31, dir = blockIdx.x >> 5;

  u32 wv[128];
  {
    const u32* wp = wpk + (size_t)dir * 131072 + tid;
    #pragma unroll
    for (int i = 0; i < 128; i++) wv[i] = wp[(size_t)i * 1024];
  }
  if (tid < 128) {
    prow_lds[tid] = perm[img * 128 + tid];
    ((__half2*)h_lds)[tid] = __float2half2_rn(0.f);
  }
  float c = 0.f;
  __syncthreads();

  const int st0 = dir ? 127 : 0;
  int prow0 = gatherPerm ? prow_lds[st0] : (img * 128 + st0);
  float pnext = P[(size_t)prow0 * 2048 + dir * 1024 + tid];

  for (int t = 0; t < 128; t++) {
    const int st = dir ? (127 - t) : t;
    float g = pnext;
    if (t < 127) {
      const int stn = dir ? (126 - t) : (t + 1);
      const int prow = gatherPerm ? prow_lds[stn] : (img * 128 + stn);
      pnext = P[(size_t)prow * 2048 + dir * 1024 + tid];
    }

    __half2 a0 = __float2half2_rn(0.f), a1 = a0, a2 = a0, a3 = a0;
    const uint4* h4 = (const uint4*)h_lds;
    #pragma unroll
    for (int q = 0; q < 32; q++) {
      uint4 hv = h4[q];
      a0 = __hfma2(u_as_h2(hv.x), u_as_h2(wv[4 * q + 0]), a0);
      a1 = __hfma2(u_as_h2(hv.y), u_as_h2(wv[4 * q + 1]), a1);
      a2 = __hfma2(u_as_h2(hv.z), u_as_h2(wv[4 * q + 2]), a2);
      a3 = __hfma2(u_as_h2(hv.w), u_as_h2(wv[4 * q + 3]), a3);
    }
    a0 = __hadd2(a0, a1); a2 = __hadd2(a2, a3); a0 = __hadd2(a0, a2);
    g += __low2float(a0) + __high2float(a0);
    g_lds[tid] = g;
    __syncthreads();

    if (tid < 256) {
      float gi = g_lds[tid], gf = g_lds[256 + tid], gg = g_lds[512 + tid], go = g_lds[768 + tid];
      float si = fsig(gi), sf = fsig(gf), so = fsig(go);
      c = sf * c + si * ftanh(gg);
      float h = so * ftanh(c);
      h_lds[tid] = __float2half(h);
      const int srow = img * 128 + st;
      const int orow = outPerm ? prow_lds[st] : srow;
      if (out_bf)  out_bf[(size_t)orow * out_ld + dir * 256 + tid] = __float2bfloat16(h);
      if (out_f32) out_f32[(size_t)orow * f32_ld + f32_off + dir * 256 + tid] = h;
    }
    __syncthreads();
  }
}

// ---------------------------------------------------------------------------
// argmax over obj_dists[:,1:151) -> preds (first max wins, like jnp.argmax)
// ---------------------------------------------------------------------------
__global__ void argmax_kernel(const float* __restrict__ dists, int* __restrict__ preds)
{
  const int row = blockIdx.x * 4 + (threadIdx.x >> 6);
  const int lane = threadIdx.x & 63;
  float best = -3.4e38f; int bi = 1000;
  for (int cc = 1 + lane; cc < 151; cc += 64) {
    float v = dists[(size_t)row * 663 + cc];
    if (v > best) { best = v; bi = cc; }
  }
  for (int off = 32; off > 0; off >>= 1) {
    float ov = __shfl_down(best, off);
    int   oi = __shfl_down(bi, off);
    if (ov > best || (ov == best && oi < bi)) { best = ov; bi = oi; }
  }
  if (lane == 0) preds[row] = bi;
}

// ---------------------------------------------------------------------------
// edge_in = [embed2[pred] (200) | enc (512, from FE) | fmaps (2048)] bf16
// ---------------------------------------------------------------------------
__global__ void edge_build(const int* __restrict__ preds,
                           const float* __restrict__ embed2,
                           const float* __restrict__ fmaps,
                           const __hip_bfloat16* __restrict__ FE,
                           __hip_bfloat16* __restrict__ EDGE)
{
  const int row = blockIdx.x, t = threadIdx.x;
  const int pr = preds[row];
  for (int c0 = t; c0 < 200; c0 += 256)
    EDGE[(size_t)row * EDGE_LD + c0] = __float2bfloat16(embed2[(size_t)pr * 200 + c0]);
  for (int c0 = t; c0 < 512; c0 += 256)
    EDGE[(size_t)row * EDGE_LD + 200 + c0] = FE[(size_t)row * FE_LD + c0];
  for (int c0 = t; c0 < 2048; c0 += 256)
    EDGE[(size_t)row * EDGE_LD + 712 + c0] = __float2bfloat16(fmaps[(size_t)row * 2048 + c0]);
}

// ---------------------------------------------------------------------------
extern "C" void kernel_launch(void* const* d_in, const int* in_sizes, int n_in,
                              void* d_out, int out_size, void* d_ws, size_t ws_size,
                              hipStream_t stream)
{
  const float* obj_fmaps    = (const float*)d_in[0];
  const float* obj_logits   = (const float*)d_in[1];
  const float* boxes        = (const float*)d_in[2];
  const float* obj_embed_w  = (const float*)d_in[4];
  const float* obj_embed2_w = (const float*)d_in[5];
  const float* bn_g = (const float*)d_in[6];
  const float* bn_b = (const float*)d_in[7];
  const float* bn_m = (const float*)d_in[8];
  const float* bn_v = (const float*)d_in[9];
  const float* pos_w = (const float*)d_in[10];
  const float* pos_b = (const float*)d_in[11];
  const float* obj_wih0 = (const float*)d_in[12];
  const float* obj_whh0 = (const float*)d_in[13];
  const float* obj_b0   = (const float*)d_in[14];
  const float* obj_wih1 = (const float*)d_in[15];
  const float* obj_whh1 = (const float*)d_in[16];
  const float* obj_b1   = (const float*)d_in[17];
  const float* edge_wih0 = (const float*)d_in[18];
  const float* edge_whh0 = (const float*)d_in[19];
  const float* edge_b0   = (const float*)d_in[20];
  const float* edge_wih1 = (const float*)d_in[21];
  const float* edge_whh1 = (const float*)d_in[22];
  const float* edge_b1   = (const float*)d_in[23];
  const float* dec_w = (const float*)d_in[24];
  const float* dec_b = (const float*)d_in[25];
  float* out = (float*)d_out;

  char* ws = (char*)d_ws;
  auto alloc = [&](size_t bytes) -> char* {
    char* p = ws; ws += (bytes + 255) & ~(size_t)255; return p;
  };
  __hip_bfloat16* FE     = (__hip_bfloat16*)alloc(4096ull * FE_LD * 2);
  __hip_bfloat16* EDGE   = (__hip_bfloat16*)alloc(4096ull * EDGE_LD * 2);
  float*          Pbuf   = (float*)alloc(4096ull * 2048 * 4);
  __hip_bfloat16* hseq   = (__hip_bfloat16*)alloc(4096ull * 512 * 2);
  __hip_bfloat16* probsb = (__hip_bfloat16*)alloc(4096ull * 192 * 2);
  __hip_bfloat16* wih0T  = (__hip_bfloat16*)alloc(2048ull * 2432 * 2);
  __hip_bfloat16* wih1T  = (__hip_bfloat16*)alloc(2048ull * 512 * 2);
  __hip_bfloat16* ewih0T = (__hip_bfloat16*)alloc(2048ull * 2816 * 2);
  __hip_bfloat16* ewih1T = (__hip_bfloat16*)alloc(2048ull * 512 * 2);
  __hip_bfloat16* embedT = (__hip_bfloat16*)alloc(256ull * 192 * 2);
  __hip_bfloat16* decT   = (__hip_bfloat16*)alloc(256ull * 2944 * 2);
  u32* whh0pk  = (u32*)alloc(2ull * 128 * 1024 * 4);
  u32* whh1pk  = (u32*)alloc(2ull * 128 * 1024 * 4);
  u32* ewhh0pk = (u32*)alloc(2ull * 128 * 1024 * 4);
  u32* ewhh1pk = (u32*)alloc(2ull * 128 * 1024 * 4);
  int*   perm  = (int*)alloc(4096 * 4);
  float* conf  = (float*)alloc(4096 * 4);
  int*   preds = (int*)alloc(4096 * 4);
  (void)in_sizes; (void)n_in; (void)out_size; (void)ws_size;

  auto tr = [&](const float* src, __hip_bfloat16* dst, int srcK, int srcN,
                int dstR, int dstC, int split, int soff) {
    dim3 g((dstC + 31) / 32, (dstR + 31) / 32);
    transpose_cast<<<g, dim3(256), 0, stream>>>(src, dst, srcK, srcN, dstR, dstC, split, soff);
  };
  for (int d = 0; d < 2; d++) {
    tr(obj_wih0 + (size_t)d * 2376 * 1024, wih0T + (size_t)d * 1024 * 2432, 2376, 1024, 1024, 2432, 0, 0);
    tr(obj_wih1 + (size_t)d * 512 * 1024,  wih1T + (size_t)d * 1024 * 512,  512, 1024, 1024, 512, 0, 0);
    tr(edge_wih0 + (size_t)d * 2760 * 1024, ewih0T + (size_t)d * 1024 * 2816, 2760, 1024, 1024, 2816, 0, 0);
    tr(edge_wih1 + (size_t)d * 512 * 1024,  ewih1T + (size_t)d * 1024 * 512,  512, 1024, 1024, 512, 0, 0);
  }
  tr(obj_embed_w, embedT, 151, 200, 256, 192, 0, 0);
  tr(dec_w, decT, 2888, 151, 256, 2944, 512, 2376);  // [enc|feats] ordering remap

  auto pk = [&](const float* whh, u32* dst) {
    pack_whh<<<dim3(4, 2), dim3(256), 0, stream>>>(whh, dst);
  };
  pk(obj_whh0, whh0pk); pk(obj_whh1, whh1pk); pk(edge_whh0, ewhh0pk); pk(edge_whh1, ewhh1pk);

  prep_kernel<<<dim3(4096), dim3(256), 0, stream>>>(
      obj_logits, obj_fmaps, boxes, bn_g, bn_b, bn_m, bn_v, pos_w, pos_b, FE, probsb, conf);
  sort_kernel<<<dim3(32), dim3(128), 0, stream>>>(conf, perm);

  auto gemm = [&](const void* A, int lda, const void* B, int ldb, int K, int N,
                  float* oF, __hip_bfloat16* oB, int ldc, const float* bias) {
    dim3 g(32, (N + 127) / 128);
    gemm_kernel<<<g, dim3(256), 0, stream>>>(
        (const u16*)A, lda, (const u16*)B, ldb, K, N, oF, oB, ldc, bias);
  };
  auto rec = [&](const float* P, const u32* wpk, int gat, int op,
                 __hip_bfloat16* ob, int old_, float* of, int fld, int foff) {
    rec_kernel<<<dim3(64), dim3(1024), 0, stream>>>(
        P, perm, wpk, gat, op, ob, old_, of, fld, foff);
  };

  // obj_embed -> FE cols [2560,2760)
  gemm(probsb, 192, embedT, 192, 192, 200, nullptr, FE + 2560, FE_LD, nullptr);
  // obj layer 0
  gemm((const u16*)FE + 512, FE_LD, wih0T, 2432, 2432, 2048, Pbuf, nullptr, 2048, obj_b0);
  rec(Pbuf, whh0pk, 1, 0, hseq, 512, nullptr, 0, 0);
  // obj layer 1 -> enc into FE cols [0,512)
  gemm(hseq, 512, wih1T, 512, 512, 2048, Pbuf, nullptr, 2048, obj_b1);
  rec(Pbuf, whh1pk, 0, 1, FE, FE_LD, nullptr, 0, 0);
  // decoder -> out cols [0,151)
  gemm(FE, FE_LD, decT, 2944, 2944, 151, out, nullptr, 663, dec_b);
  argmax_kernel<<<dim3(1024), dim3(256), 0, stream>>>(out, preds);
  edge_build<<<dim3(4096), dim3(256), 0, stream>>>(preds, obj_embed2_w, obj_fmaps, FE, EDGE);
  // edge layer 0
  gemm(EDGE, EDGE_LD, ewih0T, 2816, 2816, 2048, Pbuf, nullptr, 2048, edge_b0);
  rec(Pbuf, ewhh0pk, 1, 0, hseq, 512, nullptr, 0, 0);
  // edge layer 1 -> out cols [151,663)
  gemm(hseq, 512, ewih1T, 512, 512, 2048, Pbuf, nullptr, 2048, edge_b1);
  rec(Pbuf, ewhh1pk, 0, 1, nullptr, 0, out, 663, 151);
}

// Round 3
// 1653.604 us; speedup vs baseline: 1.1411x; 1.1384x over previous
//
#include <hip/hip_runtime.h>
#include <hip/hip_bf16.h>
#include <hip/hip_fp16.h>

typedef unsigned short u16;
typedef unsigned int u32;
typedef short s16x8 __attribute__((ext_vector_type(8)));
typedef float f32x4 __attribute__((ext_vector_type(4)));
typedef _Float16 hf2 __attribute__((ext_vector_type(2)));

#define FE_LD 2944
#define EDGE_LD 2816

static __device__ __forceinline__ hf2 u_as_hf2(u32 u){ return __builtin_bit_cast(hf2, u); }

static __device__ __forceinline__ float fsig(float x) {
  return __builtin_amdgcn_rcpf(1.f + __expf(-x));
}
static __device__ __forceinline__ float ftanh(float x) {
  return 1.f - 2.f * __builtin_amdgcn_rcpf(1.f + __expf(2.f * x));
}

#define GLD_LDS16(gsrc, ldst) \
  __builtin_amdgcn_global_load_lds((const __attribute__((address_space(1))) void*)(gsrc), \
                                   (__attribute__((address_space(3))) void*)(ldst), 16, 0, 0)

// ---------------------------------------------------------------------------
// Generic bf16 MFMA GEMM: C[M=4096][N] = A[M][K] * B^T[N][K] (+bias), K%64==0.
// 128x128 tile, 4 waves (2x2), 4x4 frags of 16x16x32.
// Staging: global_load_lds width=16, linear LDS dest + pre-swizzled source.
// ---------------------------------------------------------------------------
__global__ __launch_bounds__(256) void gemm_kernel(
    const u16* __restrict__ A, int lda,
    const u16* __restrict__ B, int ldb,
    int K, int N,
    float* __restrict__ outF, __hip_bfloat16* __restrict__ outB, int ldc,
    const float* __restrict__ bias)
{
  __shared__ __align__(16) u16 As[128*64];
  __shared__ __align__(16) u16 Bs[128*64];
  const int tid = threadIdx.x;
  const int w = tid >> 6, lane = tid & 63;
  const int wm = w >> 1, wn = w & 1;
  const long bm = (long)blockIdx.x * 128;
  const long bn = (long)blockIdx.y * 128;
  f32x4 acc[4][4] = {};

  for (int k0 = 0; k0 < K; k0 += 64) {
    #pragma unroll
    for (int rr = 0; rr < 4; rr++) {
      int idx = rr * 256 + tid;
      int row = idx >> 3;
      int g   = idx & 7;
      int gs  = g ^ (row & 7);                 // pre-swizzled source group
      int ldst = (rr * 256 + (w << 6)) * 8;    // linear wave-uniform dest (elems)
      GLD_LDS16(A + (bm + row) * (long)lda + k0 + gs * 8, &As[ldst]);
      GLD_LDS16(B + (bn + row) * (long)ldb + k0 + gs * 8, &Bs[ldst]);
    }
    __syncthreads();
    #pragma unroll
    for (int kk = 0; kk < 2; kk++) {
      s16x8 af[4], bfr[4];
      #pragma unroll
      for (int i = 0; i < 4; i++) {
        int ra = wm * 64 + i * 16 + (lane & 15);
        int rb = wn * 64 + i * 16 + (lane & 15);
        int gg = kk * 4 + (lane >> 4);
        af[i]  = *(const s16x8*)&As[ra * 64 + ((gg ^ (ra & 7)) << 3)];
        bfr[i] = *(const s16x8*)&Bs[rb * 64 + ((gg ^ (rb & 7)) << 3)];
      }
      #pragma unroll
      for (int i = 0; i < 4; i++)
        #pragma unroll
        for (int j = 0; j < 4; j++)
          acc[i][j] = __builtin_amdgcn_mfma_f32_16x16x32_bf16(af[i], bfr[j], acc[i][j], 0, 0, 0);
    }
    __syncthreads();
  }

  #pragma unroll
  for (int i = 0; i < 4; i++)
    #pragma unroll
    for (int j = 0; j < 4; j++)
      #pragma unroll
      for (int v = 0; v < 4; v++) {
        long rr = bm + wm * 64 + i * 16 + (lane >> 4) * 4 + v;
        int  cc = (int)bn + wn * 64 + j * 16 + (lane & 15);
        if (cc < N) {
          float val = acc[i][j][v] + (bias ? bias[cc] : 0.f);
          if (outF) outF[rr * (long)ldc + cc] = val;
          else      outB[rr * (long)ldc + cc] = __float2bfloat16(val);
        }
      }
}

// ---------------------------------------------------------------------------
// Tiled transpose + cast fp32 -> bf16, with zero padding and optional row
// remap (for dec: k<split -> split_off+k else k-split). dst[n][k] = src[srck][n]
// ---------------------------------------------------------------------------
__global__ void transpose_cast(const float* __restrict__ src, __hip_bfloat16* __restrict__ dst,
                               int srcK, int srcN, int dstR, int dstC, int split, int split_off)
{
  __shared__ float tile[32][33];
  const int kt = blockIdx.x * 32, nt = blockIdx.y * 32;
  const int tx = threadIdx.x & 31, ty = threadIdx.x >> 5;
  for (int i = ty; i < 32; i += 8) {
    int k = kt + i;
    int srck = (k < split) ? (split_off + k) : (k - split);
    int n = nt + tx;
    tile[i][tx] = (srck < srcK && n < srcN) ? src[(size_t)srck * srcN + n] : 0.f;
  }
  __syncthreads();
  for (int i = ty; i < 32; i += 8) {
    int n = nt + i, k = kt + tx;
    if (n < dstR && k < dstC)
      dst[(size_t)n * dstC + k] = __float2bfloat16(tile[tx][i]);
  }
}

// ---------------------------------------------------------------------------
// Pack whh fp32 [2][256][1024] -> f16 pairs, layout [dir][kk=128][col=1024]:
//   wpk[(d*128+kk)*1024 + j] = (w[2kk][j], w[2kk+1][j])
// ---------------------------------------------------------------------------
__global__ void pack_whh(const float* __restrict__ whh, u32* __restrict__ wpk)
{
  const int d = blockIdx.y;
  const int j = blockIdx.x * 256 + threadIdx.x;
  const float* s = whh + (size_t)d * 256 * 1024;
  for (int kk = 0; kk < 128; kk++) {
    __half2 h = __floats2half2_rn(s[(2 * kk) * 1024 + j], s[(2 * kk + 1) * 1024 + j]);
    wpk[((size_t)d * 128 + kk) * 1024 + j] = __builtin_bit_cast(u32, h);
  }
}

// ---------------------------------------------------------------------------
// prep: softmax(151), probs->bf16 (padded 192), conf=max(probs[1:]),
// pos = relu(BN(center_size(boxes)) @ pos_w + pos_b), fmaps -> FE bf16.
// FE layout: [enc 0..512 | fmaps 512..2560 | embed 2560..2760 | pos 2760..2888 | pad]
// ---------------------------------------------------------------------------
__global__ void prep_kernel(
    const float* __restrict__ logits, const float* __restrict__ fmaps,
    const float* __restrict__ boxes,
    const float* __restrict__ bn_g, const float* __restrict__ bn_b,
    const float* __restrict__ bn_m, const float* __restrict__ bn_v,
    const float* __restrict__ pos_w, const float* __restrict__ pos_b,
    __hip_bfloat16* __restrict__ FE, __hip_bfloat16* __restrict__ probsb,
    float* __restrict__ conf)
{
  __shared__ float red[256];
  const int row = blockIdx.x, t = threadIdx.x;
  float v = (t < 151) ? logits[(size_t)row * 151 + t] : -3.0e38f;
  red[t] = v; __syncthreads();
  for (int s = 128; s > 0; s >>= 1) { if (t < s) red[t] = fmaxf(red[t], red[t + s]); __syncthreads(); }
  float mx = red[0]; __syncthreads();
  float p = (t < 151) ? expf(v - mx) : 0.f;
  red[t] = p; __syncthreads();
  for (int s = 128; s > 0; s >>= 1) { if (t < s) red[t] += red[t + s]; __syncthreads(); }
  float sum = red[0]; __syncthreads();
  p = p / sum;
  if (t < 192) probsb[(size_t)row * 192 + t] = __float2bfloat16((t < 151) ? p : 0.f);
  red[t] = (t >= 1 && t < 151) ? p : 0.f; __syncthreads();
  for (int s = 128; s > 0; s >>= 1) { if (t < s) red[t] = fmaxf(red[t], red[t + s]); __syncthreads(); }
  if (t == 0) conf[row] = red[0];

  if (t < 128) {
    float x1 = boxes[row * 4 + 0], y1 = boxes[row * 4 + 1];
    float x2 = boxes[row * 4 + 2], y2 = boxes[row * 4 + 3];
    float cs[4] = { (x1 + x2) * 0.5f, (y1 + y2) * 0.5f, x2 - x1, y2 - y1 };
    float a = pos_b[t];
    #pragma unroll
    for (int j = 0; j < 4; j++) {
      float cn = (cs[j] - bn_m[j]) * rsqrtf(bn_v[j] + 1e-5f) * bn_g[j] + bn_b[j];
      a += cn * pos_w[j * 128 + t];
    }
    FE[(size_t)row * FE_LD + 2760 + t] = __float2bfloat16(fmaxf(a, 0.f));
  }
  for (int c0 = t; c0 < 2048; c0 += 256)
    FE[(size_t)row * FE_LD + 512 + c0] = __float2bfloat16(fmaps[(size_t)row * 2048 + c0]);
}

// ---------------------------------------------------------------------------
// Per-image bitonic sort of conf desc (tie: index asc) -> perm (global rows).
// ---------------------------------------------------------------------------
__global__ void sort_kernel(const float* __restrict__ conf, int* __restrict__ perm)
{
  __shared__ float key[128];
  __shared__ int   idx[128];
  const int b = blockIdx.x, t = threadIdx.x;
  key[t] = conf[b * 128 + t]; idx[t] = t;
  __syncthreads();
  for (int k = 2; k <= 128; k <<= 1)
    for (int j = k >> 1; j > 0; j >>= 1) {
      int ixj = t ^ j;
      if (ixj > t) {
        bool up = (t & k) == 0;
        float ka = key[t], kb = key[ixj];
        int ia = idx[t], ib = idx[ixj];
        bool before = (ka > kb) || (ka == kb && ia < ib); // desc, stable
        if (before != up) { key[t] = kb; key[ixj] = ka; idx[t] = ib; idx[ixj] = ia; }
      }
      __syncthreads();
    }
  perm[b * 128 + t] = b * 128 + idx[t];
}

// ---------------------------------------------------------------------------
// LSTM scan. 64 blocks = (img 32) x (dir 2), 1024 threads (16 waves).
// Thread j owns gate column j. whh column: 192 k-vals in 96 f16x2 VGPRs,
// 64 k-vals in LDS tail [32][1024]. v_dot2_f32_f16 inner product.
// ---------------------------------------------------------------------------
__global__ __launch_bounds__(1024, 4) void rec_kernel(
    const float* __restrict__ P,          // [4096][2048] pre-activations (+bias)
    const int* __restrict__ perm,         // [4096] global rows
    const u32* __restrict__ wpk,          // [2][128][1024]
    int gatherPerm, int outPerm,
    __hip_bfloat16* __restrict__ out_bf, int out_ld,
    float* __restrict__ out_f32, int f32_ld, int f32_off)
{
  __shared__ u32 wt[32][1024];            // 128 KB: k-pairs 96..127
  __shared__ float g_lds[1024];
  __shared__ __align__(16) __half h_lds[256];
  __shared__ int prow_lds[128];
  const int tid = threadIdx.x;
  const int img = blockIdx.x & 31, dir = blockIdx.x >> 5;

  u32 wv[96];
  {
    const u32* wp = wpk + (size_t)dir * 131072 + tid;
    #pragma unroll
    for (int i = 0; i < 96; i++) wv[i] = wp[(size_t)i * 1024];
    const u32* tp = wpk + (size_t)dir * 131072 + 96 * 1024;
    for (int i = tid; i < 32768; i += 1024) ((u32*)wt)[i] = tp[i];
  }
  if (tid < 128) {
    prow_lds[tid] = perm[img * 128 + tid];
    ((__half2*)h_lds)[tid] = __float2half2_rn(0.f);
  }
  float c = 0.f;
  __syncthreads();

  const int st0 = dir ? 127 : 0;
  int prow0 = gatherPerm ? prow_lds[st0] : (img * 128 + st0);
  float pnext = P[(size_t)prow0 * 2048 + dir * 1024 + tid];

  for (int t = 0; t < 128; t++) {
    const int st = dir ? (127 - t) : t;
    float g = pnext;
    if (t < 127) {
      const int stn = dir ? (126 - t) : (t + 1);
      const int prow = gatherPerm ? prow_lds[stn] : (img * 128 + stn);
      pnext = P[(size_t)prow * 2048 + dir * 1024 + tid];
    }

    float a0 = 0.f, a1 = 0.f, a2 = 0.f, a3 = 0.f;
    const uint4* h4 = (const uint4*)h_lds;
    #pragma unroll
    for (int q = 0; q < 24; q++) {
      uint4 hv = h4[q];
      a0 = __builtin_amdgcn_fdot2(u_as_hf2(hv.x), u_as_hf2(wv[4 * q + 0]), a0, false);
      a1 = __builtin_amdgcn_fdot2(u_as_hf2(hv.y), u_as_hf2(wv[4 * q + 1]), a1, false);
      a2 = __builtin_amdgcn_fdot2(u_as_hf2(hv.z), u_as_hf2(wv[4 * q + 2]), a2, false);
      a3 = __builtin_amdgcn_fdot2(u_as_hf2(hv.w), u_as_hf2(wv[4 * q + 3]), a3, false);
    }
    #pragma unroll
    for (int q = 24; q < 32; q++) {
      uint4 hv = h4[q];
      int kk = (q - 24) * 4;
      a0 = __builtin_amdgcn_fdot2(u_as_hf2(hv.x), u_as_hf2(wt[kk + 0][tid]), a0, false);
      a1 = __builtin_amdgcn_fdot2(u_as_hf2(hv.y), u_as_hf2(wt[kk + 1][tid]), a1, false);
      a2 = __builtin_amdgcn_fdot2(u_as_hf2(hv.z), u_as_hf2(wt[kk + 2][tid]), a2, false);
      a3 = __builtin_amdgcn_fdot2(u_as_hf2(hv.w), u_as_hf2(wt[kk + 3][tid]), a3, false);
    }
    g += (a0 + a1) + (a2 + a3);
    g_lds[tid] = g;
    __syncthreads();

    if (tid < 256) {
      float gi = g_lds[tid], gf = g_lds[256 + tid], gg = g_lds[512 + tid], go = g_lds[768 + tid];
      float si = fsig(gi), sf = fsig(gf), so = fsig(go);
      c = sf * c + si * ftanh(gg);
      float h = so * ftanh(c);
      h_lds[tid] = __float2half(h);
      const int srow = img * 128 + st;
      const int orow = outPerm ? prow_lds[st] : srow;
      if (out_bf)  out_bf[(size_t)orow * out_ld + dir * 256 + tid] = __float2bfloat16(h);
      if (out_f32) out_f32[(size_t)orow * f32_ld + f32_off + dir * 256 + tid] = h;
    }
    __syncthreads();
  }
}

// ---------------------------------------------------------------------------
// argmax over obj_dists[:,1:151) -> preds (first max wins, like jnp.argmax)
// ---------------------------------------------------------------------------
__global__ void argmax_kernel(const float* __restrict__ dists, int* __restrict__ preds)
{
  const int row = blockIdx.x * 4 + (threadIdx.x >> 6);
  const int lane = threadIdx.x & 63;
  float best = -3.4e38f; int bi = 1000;
  for (int cc = 1 + lane; cc < 151; cc += 64) {
    float v = dists[(size_t)row * 663 + cc];
    if (v > best) { best = v; bi = cc; }
  }
  for (int off = 32; off > 0; off >>= 1) {
    float ov = __shfl_down(best, off);
    int   oi = __shfl_down(bi, off);
    if (ov > best || (ov == best && oi < bi)) { best = ov; bi = oi; }
  }
  if (lane == 0) preds[row] = bi;
}

// ---------------------------------------------------------------------------
// edge_in = [embed2[pred] (200) | enc (512, from FE) | fmaps (2048)] bf16
// ---------------------------------------------------------------------------
__global__ void edge_build(const int* __restrict__ preds,
                           const float* __restrict__ embed2,
                           const float* __restrict__ fmaps,
                           const __hip_bfloat16* __restrict__ FE,
                           __hip_bfloat16* __restrict__ EDGE)
{
  const int row = blockIdx.x, t = threadIdx.x;
  const int pr = preds[row];
  for (int c0 = t; c0 < 200; c0 += 256)
    EDGE[(size_t)row * EDGE_LD + c0] = __float2bfloat16(embed2[(size_t)pr * 200 + c0]);
  for (int c0 = t; c0 < 512; c0 += 256)
    EDGE[(size_t)row * EDGE_LD + 200 + c0] = FE[(size_t)row * FE_LD + c0];
  for (int c0 = t; c0 < 2048; c0 += 256)
    EDGE[(size_t)row * EDGE_LD + 712 + c0] = __float2bfloat16(fmaps[(size_t)row * 2048 + c0]);
}

// ---------------------------------------------------------------------------
extern "C" void kernel_launch(void* const* d_in, const int* in_sizes, int n_in,
                              void* d_out, int out_size, void* d_ws, size_t ws_size,
                              hipStream_t stream)
{
  const float* obj_fmaps    = (const float*)d_in[0];
  const float* obj_logits   = (const float*)d_in[1];
  const float* boxes        = (const float*)d_in[2];
  const float* obj_embed_w  = (const float*)d_in[4];
  const float* obj_embed2_w = (const float*)d_in[5];
  const float* bn_g = (const float*)d_in[6];
  const float* bn_b = (const float*)d_in[7];
  const float* bn_m = (const float*)d_in[8];
  const float* bn_v = (const float*)d_in[9];
  const float* pos_w = (const float*)d_in[10];
  const float* pos_b = (const float*)d_in[11];
  const float* obj_wih0 = (const float*)d_in[12];
  const float* obj_whh0 = (const float*)d_in[13];
  const float* obj_b0   = (const float*)d_in[14];
  const float* obj_wih1 = (const float*)d_in[15];
  const float* obj_whh1 = (const float*)d_in[16];
  const float* obj_b1   = (const float*)d_in[17];
  const float* edge_wih0 = (const float*)d_in[18];
  const float* edge_whh0 = (const float*)d_in[19];
  const float* edge_b0   = (const float*)d_in[20];
  const float* edge_wih1 = (const float*)d_in[21];
  const float* edge_whh1 = (const float*)d_in[22];
  const float* edge_b1   = (const float*)d_in[23];
  const float* dec_w = (const float*)d_in[24];
  const float* dec_b = (const float*)d_in[25];
  float* out = (float*)d_out;

  char* ws = (char*)d_ws;
  auto alloc = [&](size_t bytes) -> char* {
    char* p = ws; ws += (bytes + 255) & ~(size_t)255; return p;
  };
  __hip_bfloat16* FE     = (__hip_bfloat16*)alloc(4096ull * FE_LD * 2);
  __hip_bfloat16* EDGE   = (__hip_bfloat16*)alloc(4096ull * EDGE_LD * 2);
  float*          Pbuf   = (float*)alloc(4096ull * 2048 * 4);
  __hip_bfloat16* hseq   = (__hip_bfloat16*)alloc(4096ull * 512 * 2);
  __hip_bfloat16* probsb = (__hip_bfloat16*)alloc(4096ull * 192 * 2);
  __hip_bfloat16* wih0T  = (__hip_bfloat16*)alloc(2048ull * 2432 * 2);
  __hip_bfloat16* wih1T  = (__hip_bfloat16*)alloc(2048ull * 512 * 2);
  __hip_bfloat16* ewih0T = (__hip_bfloat16*)alloc(2048ull * 2816 * 2);
  __hip_bfloat16* ewih1T = (__hip_bfloat16*)alloc(2048ull * 512 * 2);
  __hip_bfloat16* embedT = (__hip_bfloat16*)alloc(256ull * 192 * 2);
  __hip_bfloat16* decT   = (__hip_bfloat16*)alloc(256ull * 2944 * 2);
  u32* whh0pk  = (u32*)alloc(2ull * 128 * 1024 * 4);
  u32* whh1pk  = (u32*)alloc(2ull * 128 * 1024 * 4);
  u32* ewhh0pk = (u32*)alloc(2ull * 128 * 1024 * 4);
  u32* ewhh1pk = (u32*)alloc(2ull * 128 * 1024 * 4);
  int*   perm  = (int*)alloc(4096 * 4);
  float* conf  = (float*)alloc(4096 * 4);
  int*   preds = (int*)alloc(4096 * 4);
  (void)in_sizes; (void)n_in; (void)out_size; (void)ws_size;

  auto tr = [&](const float* src, __hip_bfloat16* dst, int srcK, int srcN,
                int dstR, int dstC, int split, int soff) {
    dim3 g((dstC + 31) / 32, (dstR + 31) / 32);
    transpose_cast<<<g, dim3(256), 0, stream>>>(src, dst, srcK, srcN, dstR, dstC, split, soff);
  };
  for (int d = 0; d < 2; d++) {
    tr(obj_wih0 + (size_t)d * 2376 * 1024, wih0T + (size_t)d * 1024 * 2432, 2376, 1024, 1024, 2432, 0, 0);
    tr(obj_wih1 + (size_t)d * 512 * 1024,  wih1T + (size_t)d * 1024 * 512,  512, 1024, 1024, 512, 0, 0);
    tr(edge_wih0 + (size_t)d * 2760 * 1024, ewih0T + (size_t)d * 1024 * 2816, 2760, 1024, 1024, 2816, 0, 0);
    tr(edge_wih1 + (size_t)d * 512 * 1024,  ewih1T + (size_t)d * 1024 * 512,  512, 1024, 1024, 512, 0, 0);
  }
  tr(obj_embed_w, embedT, 151, 200, 256, 192, 0, 0);
  tr(dec_w, decT, 2888, 151, 256, 2944, 512, 2376);  // [enc|feats] ordering remap

  auto pk = [&](const float* whh, u32* dst) {
    pack_whh<<<dim3(4, 2), dim3(256), 0, stream>>>(whh, dst);
  };
  pk(obj_whh0, whh0pk); pk(obj_whh1, whh1pk); pk(edge_whh0, ewhh0pk); pk(edge_whh1, ewhh1pk);

  prep_kernel<<<dim3(4096), dim3(256), 0, stream>>>(
      obj_logits, obj_fmaps, boxes, bn_g, bn_b, bn_m, bn_v, pos_w, pos_b, FE, probsb, conf);
  sort_kernel<<<dim3(32), dim3(128), 0, stream>>>(conf, perm);

  auto gemm = [&](const void* A, int lda, const void* B, int ldb, int K, int N,
                  float* oF, __hip_bfloat16* oB, int ldc, const float* bias) {
    dim3 g(32, (N + 127) / 128);
    gemm_kernel<<<g, dim3(256), 0, stream>>>(
        (const u16*)A, lda, (const u16*)B, ldb, K, N, oF, oB, ldc, bias);
  };
  auto rec = [&](const float* P, const u32* wpk, int gat, int op,
                 __hip_bfloat16* ob, int old_, float* of, int fld, int foff) {
    rec_kernel<<<dim3(64), dim3(1024), 0, stream>>>(
        P, perm, wpk, gat, op, ob, old_, of, fld, foff);
  };

  // obj_embed -> FE cols [2560,2760)
  gemm(probsb, 192, embedT, 192, 192, 200, nullptr, FE + 2560, FE_LD, nullptr);
  // obj layer 0
  gemm((const u16*)FE + 512, FE_LD, wih0T, 2432, 2432, 2048, Pbuf, nullptr, 2048, obj_b0);
  rec(Pbuf, whh0pk, 1, 0, hseq, 512, nullptr, 0, 0);
  // obj layer 1 -> enc into FE cols [0,512)
  gemm(hseq, 512, wih1T, 512, 512, 2048, Pbuf, nullptr, 2048, obj_b1);
  rec(Pbuf, whh1pk, 0, 1, FE, FE_LD, nullptr, 0, 0);
  // decoder -> out cols [0,151)
  gemm(FE, FE_LD, decT, 2944, 2944, 151, out, nullptr, 663, dec_b);
  argmax_kernel<<<dim3(1024), dim3(256), 0, stream>>>(out, preds);
  edge_build<<<dim3(4096), dim3(256), 0, stream>>>(preds, obj_embed2_w, obj_fmaps, FE, EDGE);
  // edge layer 0
  gemm(EDGE, EDGE_LD, ewih0T, 2816, 2816, 2048, Pbuf, nullptr, 2048, edge_b0);
  rec(Pbuf, ewhh0pk, 1, 0, hseq, 512, nullptr, 0, 0);
  // edge layer 1 -> out cols [151,663)
  gemm(hseq, 512, ewih1T, 512, 512, 2048, Pbuf, nullptr, 2048, edge_b1);
  rec(Pbuf, ewhh1pk, 0, 1, nullptr, 0, out, 663, 151);
}

// Round 4
// 1521.566 us; speedup vs baseline: 1.2401x; 1.0868x over previous
//
#include <hip/hip_runtime.h>
#include <hip/hip_bf16.h>
#include <hip/hip_fp16.h>

typedef unsigned short u16;
typedef unsigned int u32;
typedef short s16x8 __attribute__((ext_vector_type(8)));
typedef float f32x4 __attribute__((ext_vector_type(4)));
typedef _Float16 hf2 __attribute__((ext_vector_type(2)));

#define FE_LD 2944
#define EDGE_LD 2816

static __device__ __forceinline__ hf2 u_as_hf2(u32 u){ return __builtin_bit_cast(hf2, u); }
static __device__ __forceinline__ float fdot2(u32 a, u32 b, float acc) {
  return __builtin_amdgcn_fdot2(u_as_hf2(a), u_as_hf2(b), acc, false);
}

static __device__ __forceinline__ float fsig(float x) {
  return __builtin_amdgcn_rcpf(1.f + __expf(-x));
}
static __device__ __forceinline__ float ftanh(float x) {
  return 1.f - 2.f * __builtin_amdgcn_rcpf(1.f + __expf(2.f * x));
}

#define GLD_LDS16(gsrc, ldst) \
  __builtin_amdgcn_global_load_lds((const __attribute__((address_space(1))) void*)(gsrc), \
                                   (__attribute__((address_space(3))) void*)(ldst), 16, 0, 0)

// ---------------------------------------------------------------------------
// Generic bf16 MFMA GEMM: C[M=4096][N] = A[M][K] * B^T[N][K] (+bias), K%64==0.
// 128x128 tile, 4 waves (2x2), 4x4 frags of 16x16x32.
// Staging: global_load_lds width=16, linear LDS dest + pre-swizzled source.
// ---------------------------------------------------------------------------
__global__ __launch_bounds__(256) void gemm_kernel(
    const u16* __restrict__ A, int lda,
    const u16* __restrict__ B, int ldb,
    int K, int N,
    float* __restrict__ outF, __hip_bfloat16* __restrict__ outB, int ldc,
    const float* __restrict__ bias)
{
  __shared__ __align__(16) u16 As[128*64];
  __shared__ __align__(16) u16 Bs[128*64];
  const int tid = threadIdx.x;
  const int w = tid >> 6, lane = tid & 63;
  const int wm = w >> 1, wn = w & 1;
  const long bm = (long)blockIdx.x * 128;
  const long bn = (long)blockIdx.y * 128;
  f32x4 acc[4][4] = {};

  for (int k0 = 0; k0 < K; k0 += 64) {
    #pragma unroll
    for (int rr = 0; rr < 4; rr++) {
      int idx = rr * 256 + tid;
      int row = idx >> 3;
      int g   = idx & 7;
      int gs  = g ^ (row & 7);                 // pre-swizzled source group
      int ldst = (rr * 256 + (w << 6)) * 8;    // linear wave-uniform dest (elems)
      GLD_LDS16(A + (bm + row) * (long)lda + k0 + gs * 8, &As[ldst]);
      GLD_LDS16(B + (bn + row) * (long)ldb + k0 + gs * 8, &Bs[ldst]);
    }
    __syncthreads();
    #pragma unroll
    for (int kk = 0; kk < 2; kk++) {
      s16x8 af[4], bfr[4];
      #pragma unroll
      for (int i = 0; i < 4; i++) {
        int ra = wm * 64 + i * 16 + (lane & 15);
        int rb = wn * 64 + i * 16 + (lane & 15);
        int gg = kk * 4 + (lane >> 4);
        af[i]  = *(const s16x8*)&As[ra * 64 + ((gg ^ (ra & 7)) << 3)];
        bfr[i] = *(const s16x8*)&Bs[rb * 64 + ((gg ^ (rb & 7)) << 3)];
      }
      #pragma unroll
      for (int i = 0; i < 4; i++)
        #pragma unroll
        for (int j = 0; j < 4; j++)
          acc[i][j] = __builtin_amdgcn_mfma_f32_16x16x32_bf16(af[i], bfr[j], acc[i][j], 0, 0, 0);
    }
    __syncthreads();
  }

  #pragma unroll
  for (int i = 0; i < 4; i++)
    #pragma unroll
    for (int j = 0; j < 4; j++)
      #pragma unroll
      for (int v = 0; v < 4; v++) {
        long rr = bm + wm * 64 + i * 16 + (lane >> 4) * 4 + v;
        int  cc = (int)bn + wn * 64 + j * 16 + (lane & 15);
        if (cc < N) {
          float val = acc[i][j][v] + (bias ? bias[cc] : 0.f);
          if (outF) outF[rr * (long)ldc + cc] = val;
          else      outB[rr * (long)ldc + cc] = __float2bfloat16(val);
        }
      }
}

// ---------------------------------------------------------------------------
// Tiled transpose + cast fp32 -> bf16, zero pad, optional row remap.
// dst[n][k] = src[srck][n]
// ---------------------------------------------------------------------------
__global__ void transpose_cast(const float* __restrict__ src, __hip_bfloat16* __restrict__ dst,
                               int srcK, int srcN, int dstR, int dstC, int split, int split_off)
{
  __shared__ float tile[32][33];
  const int kt = blockIdx.x * 32, nt = blockIdx.y * 32;
  const int tx = threadIdx.x & 31, ty = threadIdx.x >> 5;
  for (int i = ty; i < 32; i += 8) {
    int k = kt + i;
    int srck = (k < split) ? (split_off + k) : (k - split);
    int n = nt + tx;
    tile[i][tx] = (srck < srcK && n < srcN) ? src[(size_t)srck * srcN + n] : 0.f;
  }
  __syncthreads();
  for (int i = ty; i < 32; i += 8) {
    int n = nt + i, k = kt + tx;
    if (n < dstR && k < dstC)
      dst[(size_t)n * dstC + k] = __float2bfloat16(tile[tx][i]);
  }
}

// ---------------------------------------------------------------------------
// Pack whh fp32 [2][256][1024] -> f16 pairs for the kg-split rec kernel.
// Thread (kg=tid>>8, jj=tid&255) owns, for gate g, col g*256+jj, pairs
// p=0..31 over k in [kg*64, kg*64+64).
//   res[d][p 0..15][g][tid]          (resident: 64 u32/thread)
//   str[d][c 0..7][tid][g]           (streamed: pair 16+c, dwordx4/thread)
//   tg [d][q 0..7][g][tid]           (LDS tail:  pair 24+q)
// ---------------------------------------------------------------------------
__global__ void pack_whh(const float* __restrict__ whh, u32* __restrict__ res,
                         u32* __restrict__ str, u32* __restrict__ tg)
{
  const int d = blockIdx.y;
  const int tid = blockIdx.x * 256 + threadIdx.x;   // 0..1023
  const int kg = tid >> 8, jj = tid & 255;
  const float* s = whh + (size_t)d * 256 * 1024;
  for (int p = 0; p < 16; p++)
    for (int g = 0; g < 4; g++) {
      int k0 = kg * 64 + 2 * p, col = g * 256 + jj;
      __half2 h = __floats2half2_rn(s[(size_t)k0 * 1024 + col], s[(size_t)(k0 + 1) * 1024 + col]);
      res[((size_t)(d * 16 + p) * 4 + g) * 1024 + tid] = __builtin_bit_cast(u32, h);
    }
  for (int c = 0; c < 8; c++)
    for (int g = 0; g < 4; g++) {
      int k0 = kg * 64 + 2 * (16 + c), col = g * 256 + jj;
      __half2 h = __floats2half2_rn(s[(size_t)k0 * 1024 + col], s[(size_t)(k0 + 1) * 1024 + col]);
      str[((size_t)(d * 8 + c) * 1024 + tid) * 4 + g] = __builtin_bit_cast(u32, h);
    }
  for (int q = 0; q < 8; q++)
    for (int g = 0; g < 4; g++) {
      int k0 = kg * 64 + 2 * (24 + q), col = g * 256 + jj;
      __half2 h = __floats2half2_rn(s[(size_t)k0 * 1024 + col], s[(size_t)(k0 + 1) * 1024 + col]);
      tg[((size_t)(d * 8 + q) * 4 + g) * 1024 + tid] = __builtin_bit_cast(u32, h);
    }
}

// ---------------------------------------------------------------------------
// prep: softmax(151), probs->bf16 (padded 192), conf=max(probs[1:]),
// pos = relu(BN(center_size(boxes)) @ pos_w + pos_b), fmaps -> FE bf16.
// FE layout: [enc 0..512 | fmaps 512..2560 | embed 2560..2760 | pos 2760..2888 | pad]
// ---------------------------------------------------------------------------
__global__ void prep_kernel(
    const float* __restrict__ logits, const float* __restrict__ fmaps,
    const float* __restrict__ boxes,
    const float* __restrict__ bn_g, const float* __restrict__ bn_b,
    const float* __restrict__ bn_m, const float* __restrict__ bn_v,
    const float* __restrict__ pos_w, const float* __restrict__ pos_b,
    __hip_bfloat16* __restrict__ FE, __hip_bfloat16* __restrict__ probsb,
    float* __restrict__ conf)
{
  __shared__ float red[256];
  const int row = blockIdx.x, t = threadIdx.x;
  float v = (t < 151) ? logits[(size_t)row * 151 + t] : -3.0e38f;
  red[t] = v; __syncthreads();
  for (int s = 128; s > 0; s >>= 1) { if (t < s) red[t] = fmaxf(red[t], red[t + s]); __syncthreads(); }
  float mx = red[0]; __syncthreads();
  float p = (t < 151) ? expf(v - mx) : 0.f;
  red[t] = p; __syncthreads();
  for (int s = 128; s > 0; s >>= 1) { if (t < s) red[t] += red[t + s]; __syncthreads(); }
  float sum = red[0]; __syncthreads();
  p = p / sum;
  if (t < 192) probsb[(size_t)row * 192 + t] = __float2bfloat16((t < 151) ? p : 0.f);
  red[t] = (t >= 1 && t < 151) ? p : 0.f; __syncthreads();
  for (int s = 128; s > 0; s >>= 1) { if (t < s) red[t] = fmaxf(red[t], red[t + s]); __syncthreads(); }
  if (t == 0) conf[row] = red[0];

  if (t < 128) {
    float x1 = boxes[row * 4 + 0], y1 = boxes[row * 4 + 1];
    float x2 = boxes[row * 4 + 2], y2 = boxes[row * 4 + 3];
    float cs[4] = { (x1 + x2) * 0.5f, (y1 + y2) * 0.5f, x2 - x1, y2 - y1 };
    float a = pos_b[t];
    #pragma unroll
    for (int j = 0; j < 4; j++) {
      float cn = (cs[j] - bn_m[j]) * rsqrtf(bn_v[j] + 1e-5f) * bn_g[j] + bn_b[j];
      a += cn * pos_w[j * 128 + t];
    }
    FE[(size_t)row * FE_LD + 2760 + t] = __float2bfloat16(fmaxf(a, 0.f));
  }
  for (int c0 = t; c0 < 2048; c0 += 256)
    FE[(size_t)row * FE_LD + 512 + c0] = __float2bfloat16(fmaps[(size_t)row * 2048 + c0]);
}

// ---------------------------------------------------------------------------
// Per-image bitonic sort of conf desc (tie: index asc) -> perm (global rows).
// ---------------------------------------------------------------------------
__global__ void sort_kernel(const float* __restrict__ conf, int* __restrict__ perm)
{
  __shared__ float key[128];
  __shared__ int   idx[128];
  const int b = blockIdx.x, t = threadIdx.x;
  key[t] = conf[b * 128 + t]; idx[t] = t;
  __syncthreads();
  for (int k = 2; k <= 128; k <<= 1)
    for (int j = k >> 1; j > 0; j >>= 1) {
      int ixj = t ^ j;
      if (ixj > t) {
        bool up = (t & k) == 0;
        float ka = key[t], kb = key[ixj];
        int ia = idx[t], ib = idx[ixj];
        bool before = (ka > kb) || (ka == kb && ia < ib); // desc, stable
        if (before != up) { key[t] = kb; key[ixj] = ka; idx[t] = ib; idx[ixj] = ia; }
      }
      __syncthreads();
    }
  perm[b * 128 + t] = b * 128 + idx[t];
}

// ---------------------------------------------------------------------------
// LSTM scan, kg-split. 64 blocks = (img 32) x (dir 2), 1024 threads.
// Thread (kg=tid>>8, j=tid&255): partial dots of all 4 gates of h-dim j over
// k in [kg*64, kg*64+64). Weights: 64 u32 pinned VGPR + 8 dwordx4 streamed
// (L2) + 8 pairs in XOR-swizzled LDS. Gate reduce via 12KB LDS partials.
// ---------------------------------------------------------------------------
__global__ __launch_bounds__(1024, 4) void rec_kernel(
    const float* __restrict__ P,          // [4096][2048] pre-activations (+bias)
    const int* __restrict__ perm,         // [4096] global rows
    const u32* __restrict__ wres, const u32* __restrict__ wstr, const u32* __restrict__ wtg,
    int gatherPerm, int outPerm,
    __hip_bfloat16* __restrict__ out_bf, int out_ld,
    float* __restrict__ out_f32, int f32_ld, int f32_off)
{
  __shared__ __align__(16) u32 wt[1024 * 32];    // 128 KB tail (pairs 24..31)
  __shared__ __align__(16) f32x4 part[768];      // 12 KB gate partials (kg 1..3)
  __shared__ __align__(16) __half h_lds[256];
  __shared__ int prow_lds[128];
  const int tid = threadIdx.x;
  const int kg = tid >> 8, jj = tid & 255;
  const int img = blockIdx.x & 31, dir = blockIdx.x >> 5;

  u32 wv[64];
  {
    const u32* rp = wres + (size_t)dir * 65536 + tid;
    #pragma unroll
    for (int i = 0; i < 64; i++) wv[i] = rp[(size_t)i * 1024];
  }
  #pragma unroll
  for (int i = 0; i < 64; i++) asm volatile("" : "+v"(wv[i]));   // forbid remat
  {
    const u32* tp = wtg + (size_t)dir * 32768 + tid;
    #pragma unroll
    for (int q = 0; q < 8; q++) {
      int sq = ((q ^ (tid & 7)) << 2);
      #pragma unroll
      for (int g = 0; g < 4; g++)
        wt[tid * 32 + sq + g] = tp[(size_t)(q * 4 + g) * 1024];
    }
  }
  if (tid < 128) prow_lds[tid] = perm[img * 128 + tid];
  if (tid < 256) h_lds[tid] = __float2half(0.f);
  float c = 0.f;
  __syncthreads();

  const u32* sp = wstr + ((size_t)dir * 8192 + tid) * 4;
  const uint4* h4 = (const uint4*)h_lds;
  const int pbase = dir * 1024 + kg * 256 + jj;

  int st = dir ? 127 : 0;
  {
    int prow = gatherPerm ? prow_lds[st] : (img * 128 + st);
    asm volatile("" : "+v"(prow));
  }
  int prow0 = gatherPerm ? prow_lds[st] : (img * 128 + st);
  float pcur = P[(size_t)prow0 * 2048 + pbase];

  for (int t = 0; t < 128; t++) {
    float pnext = 0.f;
    if (t < 127) {
      int stn = dir ? (126 - t) : (t + 1);
      int prn = gatherPerm ? prow_lds[stn] : (img * 128 + stn);
      pnext = P[(size_t)prn * 2048 + pbase];
    }
    float g0 = (kg == 0) ? pcur : 0.f;
    float g1 = (kg == 1) ? pcur : 0.f;
    float g2 = (kg == 2) ? pcur : 0.f;
    float g3 = (kg == 3) ? pcur : 0.f;

    // window A of streamed weights (pairs 16..19)
    uint4 swA0 = *(const uint4*)(sp + 0 * 4096);
    uint4 swA1 = *(const uint4*)(sp + 1 * 4096);
    uint4 swA2 = *(const uint4*)(sp + 2 * 4096);
    uint4 swA3 = *(const uint4*)(sp + 3 * 4096);

    // resident pairs 0..15
    #pragma unroll
    for (int cc = 0; cc < 4; cc++) {
      uint4 hv = h4[kg * 8 + cc];
      #pragma unroll
      for (int s = 0; s < 4; s++) {
        int p = cc * 4 + s;
        u32 hp = (s == 0) ? hv.x : (s == 1) ? hv.y : (s == 2) ? hv.z : hv.w;
        g0 = fdot2(hp, wv[p * 4 + 0], g0);
        g1 = fdot2(hp, wv[p * 4 + 1], g1);
        g2 = fdot2(hp, wv[p * 4 + 2], g2);
        g3 = fdot2(hp, wv[p * 4 + 3], g3);
      }
    }
    __builtin_amdgcn_sched_barrier(0);
    // window B issued; consume A (h chunk 4), then LDS tail (h chunks 6,7)
    uint4 swB0 = *(const uint4*)(sp + 4 * 4096);
    uint4 swB1 = *(const uint4*)(sp + 5 * 4096);
    uint4 swB2 = *(const uint4*)(sp + 6 * 4096);
    uint4 swB3 = *(const uint4*)(sp + 7 * 4096);
    {
      uint4 hv = h4[kg * 8 + 4];
      g0 = fdot2(hv.x, swA0.x, g0); g1 = fdot2(hv.x, swA0.y, g1);
      g2 = fdot2(hv.x, swA0.z, g2); g3 = fdot2(hv.x, swA0.w, g3);
      g0 = fdot2(hv.y, swA1.x, g0); g1 = fdot2(hv.y, swA1.y, g1);
      g2 = fdot2(hv.y, swA1.z, g2); g3 = fdot2(hv.y, swA1.w, g3);
      g0 = fdot2(hv.z, swA2.x, g0); g1 = fdot2(hv.z, swA2.y, g1);
      g2 = fdot2(hv.z, swA2.z, g2); g3 = fdot2(hv.z, swA2.w, g3);
      g0 = fdot2(hv.w, swA3.x, g0); g1 = fdot2(hv.w, swA3.y, g1);
      g2 = fdot2(hv.w, swA3.z, g2); g3 = fdot2(hv.w, swA3.w, g3);
    }
    {
      uint4 hv6 = h4[kg * 8 + 6];
      uint4 hv7 = h4[kg * 8 + 7];
      #pragma unroll
      for (int q = 0; q < 8; q++) {
        uint4 tw = *(const uint4*)&wt[tid * 32 + ((q ^ (tid & 7)) << 2)];
        uint4 hv = (q < 4) ? hv6 : hv7;
        int s = q & 3;
        u32 hp = (s == 0) ? hv.x : (s == 1) ? hv.y : (s == 2) ? hv.z : hv.w;
        g0 = fdot2(hp, tw.x, g0); g1 = fdot2(hp, tw.y, g1);
        g2 = fdot2(hp, tw.z, g2); g3 = fdot2(hp, tw.w, g3);
      }
    }
    __builtin_amdgcn_sched_barrier(0);
    {
      uint4 hv = h4[kg * 8 + 5];
      g0 = fdot2(hv.x, swB0.x, g0); g1 = fdot2(hv.x, swB0.y, g1);
      g2 = fdot2(hv.x, swB0.z, g2); g3 = fdot2(hv.x, swB0.w, g3);
      g0 = fdot2(hv.y, swB1.x, g0); g1 = fdot2(hv.y, swB1.y, g1);
      g2 = fdot2(hv.y, swB1.z, g2); g3 = fdot2(hv.y, swB1.w, g3);
      g0 = fdot2(hv.z, swB2.x, g0); g1 = fdot2(hv.z, swB2.y, g1);
      g2 = fdot2(hv.z, swB2.z, g2); g3 = fdot2(hv.z, swB2.w, g3);
      g0 = fdot2(hv.w, swB3.x, g0); g1 = fdot2(hv.w, swB3.y, g1);
      g2 = fdot2(hv.w, swB3.z, g2); g3 = fdot2(hv.w, swB3.w, g3);
    }

    if (kg != 0) part[(kg - 1) * 256 + jj] = f32x4{g0, g1, g2, g3};
    __syncthreads();

    if (tid < 256) {
      f32x4 t0 = part[tid], t1 = part[256 + tid], t2 = part[512 + tid];
      float gi = g0 + t0[0] + t1[0] + t2[0];
      float gf = g1 + t0[1] + t1[1] + t2[1];
      float gg = g2 + t0[2] + t1[2] + t2[2];
      float go = g3 + t0[3] + t1[3] + t2[3];
      float si = fsig(gi), sf = fsig(gf), so = fsig(go);
      c = sf * c + si * ftanh(gg);
      float h = so * ftanh(c);
      h_lds[tid] = __float2half(h);
      const int orow = outPerm ? prow_lds[st] : (img * 128 + st);
      if (out_bf)  out_bf[(size_t)orow * out_ld + dir * 256 + tid] = __float2bfloat16(h);
      if (out_f32) out_f32[(size_t)orow * f32_ld + f32_off + dir * 256 + tid] = h;
    }
    __syncthreads();
    pcur = pnext;
    st = dir ? (st - 1) : (st + 1);
  }
}

// ---------------------------------------------------------------------------
// argmax over obj_dists[:,1:151) -> preds (first max wins, like jnp.argmax)
// ---------------------------------------------------------------------------
__global__ void argmax_kernel(const float* __restrict__ dists, int* __restrict__ preds)
{
  const int row = blockIdx.x * 4 + (threadIdx.x >> 6);
  const int lane = threadIdx.x & 63;
  float best = -3.4e38f; int bi = 1000;
  for (int cc = 1 + lane; cc < 151; cc += 64) {
    float v = dists[(size_t)row * 663 + cc];
    if (v > best) { best = v; bi = cc; }
  }
  for (int off = 32; off > 0; off >>= 1) {
    float ov = __shfl_down(best, off);
    int   oi = __shfl_down(bi, off);
    if (ov > best || (ov == best && oi < bi)) { best = ov; bi = oi; }
  }
  if (lane == 0) preds[row] = bi;
}

// ---------------------------------------------------------------------------
// edge_in = [embed2[pred] (200) | enc (512, from FE) | fmaps (2048)] bf16
// ---------------------------------------------------------------------------
__global__ void edge_build(const int* __restrict__ preds,
                           const float* __restrict__ embed2,
                           const float* __restrict__ fmaps,
                           const __hip_bfloat16* __restrict__ FE,
                           __hip_bfloat16* __restrict__ EDGE)
{
  const int row = blockIdx.x, t = threadIdx.x;
  const int pr = preds[row];
  for (int c0 = t; c0 < 200; c0 += 256)
    EDGE[(size_t)row * EDGE_LD + c0] = __float2bfloat16(embed2[(size_t)pr * 200 + c0]);
  for (int c0 = t; c0 < 512; c0 += 256)
    EDGE[(size_t)row * EDGE_LD + 200 + c0] = FE[(size_t)row * FE_LD + c0];
  for (int c0 = t; c0 < 2048; c0 += 256)
    EDGE[(size_t)row * EDGE_LD + 712 + c0] = __float2bfloat16(fmaps[(size_t)row * 2048 + c0]);
}

// ---------------------------------------------------------------------------
extern "C" void kernel_launch(void* const* d_in, const int* in_sizes, int n_in,
                              void* d_out, int out_size, void* d_ws, size_t ws_size,
                              hipStream_t stream)
{
  const float* obj_fmaps    = (const float*)d_in[0];
  const float* obj_logits   = (const float*)d_in[1];
  const float* boxes        = (const float*)d_in[2];
  const float* obj_embed_w  = (const float*)d_in[4];
  const float* obj_embed2_w = (const float*)d_in[5];
  const float* bn_g = (const float*)d_in[6];
  const float* bn_b = (const float*)d_in[7];
  const float* bn_m = (const float*)d_in[8];
  const float* bn_v = (const float*)d_in[9];
  const float* pos_w = (const float*)d_in[10];
  const float* pos_b = (const float*)d_in[11];
  const float* obj_wih0 = (const float*)d_in[12];
  const float* obj_whh0 = (const float*)d_in[13];
  const float* obj_b0   = (const float*)d_in[14];
  const float* obj_wih1 = (const float*)d_in[15];
  const float* obj_whh1 = (const float*)d_in[16];
  const float* obj_b1   = (const float*)d_in[17];
  const float* edge_wih0 = (const float*)d_in[18];
  const float* edge_whh0 = (const float*)d_in[19];
  const float* edge_b0   = (const float*)d_in[20];
  const float* edge_wih1 = (const float*)d_in[21];
  const float* edge_whh1 = (const float*)d_in[22];
  const float* edge_b1   = (const float*)d_in[23];
  const float* dec_w = (const float*)d_in[24];
  const float* dec_b = (const float*)d_in[25];
  float* out = (float*)d_out;

  char* ws = (char*)d_ws;
  auto alloc = [&](size_t bytes) -> char* {
    char* p = ws; ws += (bytes + 255) & ~(size_t)255; return p;
  };
  __hip_bfloat16* FE     = (__hip_bfloat16*)alloc(4096ull * FE_LD * 2);
  __hip_bfloat16* EDGE   = (__hip_bfloat16*)alloc(4096ull * EDGE_LD * 2);
  float*          Pbuf   = (float*)alloc(4096ull * 2048 * 4);
  __hip_bfloat16* hseq   = (__hip_bfloat16*)alloc(4096ull * 512 * 2);
  __hip_bfloat16* probsb = (__hip_bfloat16*)alloc(4096ull * 192 * 2);
  __hip_bfloat16* wih0T  = (__hip_bfloat16*)alloc(2048ull * 2432 * 2);
  __hip_bfloat16* wih1T  = (__hip_bfloat16*)alloc(2048ull * 512 * 2);
  __hip_bfloat16* ewih0T = (__hip_bfloat16*)alloc(2048ull * 2816 * 2);
  __hip_bfloat16* ewih1T = (__hip_bfloat16*)alloc(2048ull * 512 * 2);
  __hip_bfloat16* embedT = (__hip_bfloat16*)alloc(256ull * 192 * 2);
  __hip_bfloat16* decT   = (__hip_bfloat16*)alloc(256ull * 2944 * 2);
  // each packed whh set: res 131072 u32 | str 65536 u32 | tg 65536 u32
  u32* whh0pk  = (u32*)alloc(262144ull * 4);
  u32* whh1pk  = (u32*)alloc(262144ull * 4);
  u32* ewhh0pk = (u32*)alloc(262144ull * 4);
  u32* ewhh1pk = (u32*)alloc(262144ull * 4);
  int*   perm  = (int*)alloc(4096 * 4);
  float* conf  = (float*)alloc(4096 * 4);
  int*   preds = (int*)alloc(4096 * 4);
  (void)in_sizes; (void)n_in; (void)out_size; (void)ws_size;

  auto tr = [&](const float* src, __hip_bfloat16* dst, int srcK, int srcN,
                int dstR, int dstC, int split, int soff) {
    dim3 g((dstC + 31) / 32, (dstR + 31) / 32);
    transpose_cast<<<g, dim3(256), 0, stream>>>(src, dst, srcK, srcN, dstR, dstC, split, soff);
  };
  for (int d = 0; d < 2; d++) {
    tr(obj_wih0 + (size_t)d * 2376 * 1024, wih0T + (size_t)d * 1024 * 2432, 2376, 1024, 1024, 2432, 0, 0);
    tr(obj_wih1 + (size_t)d * 512 * 1024,  wih1T + (size_t)d * 1024 * 512,  512, 1024, 1024, 512, 0, 0);
    tr(edge_wih0 + (size_t)d * 2760 * 1024, ewih0T + (size_t)d * 1024 * 2816, 2760, 1024, 1024, 2816, 0, 0);
    tr(edge_wih1 + (size_t)d * 512 * 1024,  ewih1T + (size_t)d * 1024 * 512,  512, 1024, 1024, 512, 0, 0);
  }
  tr(obj_embed_w, embedT, 151, 200, 256, 192, 0, 0);
  tr(dec_w, decT, 2888, 151, 256, 2944, 512, 2376);  // [enc|feats] ordering remap

  auto pk = [&](const float* whh, u32* dst) {
    pack_whh<<<dim3(4, 2), dim3(256), 0, stream>>>(whh, dst, dst + 131072, dst + 196608);
  };
  pk(obj_whh0, whh0pk); pk(obj_whh1, whh1pk); pk(edge_whh0, ewhh0pk); pk(edge_whh1, ewhh1pk);

  prep_kernel<<<dim3(4096), dim3(256), 0, stream>>>(
      obj_logits, obj_fmaps, boxes, bn_g, bn_b, bn_m, bn_v, pos_w, pos_b, FE, probsb, conf);
  sort_kernel<<<dim3(32), dim3(128), 0, stream>>>(conf, perm);

  auto gemm = [&](const void* A, int lda, const void* B, int ldb, int K, int N,
                  float* oF, __hip_bfloat16* oB, int ldc, const float* bias) {
    dim3 g(32, (N + 127) / 128);
    gemm_kernel<<<g, dim3(256), 0, stream>>>(
        (const u16*)A, lda, (const u16*)B, ldb, K, N, oF, oB, ldc, bias);
  };
  auto rec = [&](const float* P, const u32* wpk, int gat, int op,
                 __hip_bfloat16* ob, int old_, float* of, int fld, int foff) {
    rec_kernel<<<dim3(64), dim3(1024), 0, stream>>>(
        P, perm, wpk, wpk + 131072, wpk + 196608, gat, op, ob, old_, of, fld, foff);
  };

  // obj_embed -> FE cols [2560,2760)
  gemm(probsb, 192, embedT, 192, 192, 200, nullptr, FE + 2560, FE_LD, nullptr);
  // obj layer 0
  gemm((const u16*)FE + 512, FE_LD, wih0T, 2432, 2432, 2048, Pbuf, nullptr, 2048, obj_b0);
  rec(Pbuf, whh0pk, 1, 0, hseq, 512, nullptr, 0, 0);
  // obj layer 1 -> enc into FE cols [0,512)
  gemm(hseq, 512, wih1T, 512, 512, 2048, Pbuf, nullptr, 2048, obj_b1);
  rec(Pbuf, whh1pk, 0, 1, FE, FE_LD, nullptr, 0, 0);
  // decoder -> out cols [0,151)
  gemm(FE, FE_LD, decT, 2944, 2944, 151, out, nullptr, 663, dec_b);
  argmax_kernel<<<dim3(1024), dim3(256), 0, stream>>>(out, preds);
  edge_build<<<dim3(4096), dim3(256), 0, stream>>>(preds, obj_embed2_w, obj_fmaps, FE, EDGE);
  // edge layer 0
  gemm(EDGE, EDGE_LD, ewih0T, 2816, 2816, 2048, Pbuf, nullptr, 2048, edge_b0);
  rec(Pbuf, ewhh0pk, 1, 0, hseq, 512, nullptr, 0, 0);
  // edge layer 1 -> out cols [151,663)
  gemm(hseq, 512, ewih1T, 512, 512, 2048, Pbuf, nullptr, 2048, edge_b1);
  rec(Pbuf, ewhh1pk, 0, 1, nullptr, 0, out, 663, 151);
}